// Round 11
// baseline (102.163 us; speedup 1.0000x reference)
//
#include <hip/hip_runtime.h>
#include <hip/hip_bf16.h>
#include <stdint.h>

// B=8192 triplet loss with hard-negative mining.
// prep: normalize -> bf16
// dist_topk: LDS double-buffered GEMM (2-phase). 64x256 tile, BK=32, 8
//            K-steps, 8 waves each 64 rows x 32 cols -> acc[4][2] = 32 AGPR
//            (R8-R10 spilled with 64-AGPR waves: 128-reg budget leaves only
//            64 VGPRs). Paired-row XOR swizzle (0 conflicts, R10-proven).
//            Epilogue: mine -> cross-hi shuffle merge -> mls in buf0 ->
//            per-row merge. NCG=32 unchanged.
// merge_loss: merge 32 sorted runs (4 rows/block), JAX threefry RNG,
//             exact fp32 loss per row
// finalize: deterministic mean

#define NB 8192
#define NCG 32        // col-groups of 256
#define EPSF 1e-6f

typedef float f32x4 __attribute__((ext_vector_type(4)));
typedef short short8 __attribute__((ext_vector_type(8)));

struct U2 { uint32_t x, y; };

__host__ __device__ __forceinline__ uint32_t rotl32(uint32_t v, int n) {
  return (v << n) | (v >> (32 - n));
}

__host__ __device__ __forceinline__ U2 tf2x32(uint32_t k0, uint32_t k1,
                                              uint32_t x0, uint32_t x1) {
  uint32_t k2 = k0 ^ k1 ^ 0x1BD11BDAu;
#define TF_R(r) { x0 += x1; x1 = rotl32(x1, r); x1 ^= x0; }
  x0 += k0; x1 += k1;
  TF_R(13) TF_R(15) TF_R(26) TF_R(6)
  x0 += k1; x1 += k2 + 1u;
  TF_R(17) TF_R(29) TF_R(16) TF_R(24)
  x0 += k2; x1 += k0 + 2u;
  TF_R(13) TF_R(15) TF_R(26) TF_R(6)
  x0 += k0; x1 += k1 + 3u;
  TF_R(17) TF_R(29) TF_R(16) TF_R(24)
  x0 += k1; x1 += k2 + 4u;
  TF_R(13) TF_R(15) TF_R(26) TF_R(6)
  x0 += k2; x1 += k0 + 5u;
#undef TF_R
  U2 r; r.x = x0; r.y = x1; return r;
}

__device__ __forceinline__ uint32_t rng_word(U2 r) { return r.x ^ r.y; }

// float insertion into sorted-desc top-5 (keys are positive floats, so
// float order == u32 order); 5 independent ops.
#define FINS5(T0, T1, T2, T3, T4, C) {            \
    const float _t0 = T0, _t1 = T1, _t2 = T2, _t3 = T3, _t4 = T4, _c = C; \
    T0 = fmaxf(_t0, _c);                          \
    T1 = __builtin_amdgcn_fmed3f(_c, _t0, _t1);   \
    T2 = __builtin_amdgcn_fmed3f(_c, _t1, _t2);   \
    T3 = __builtin_amdgcn_fmed3f(_c, _t2, _t3);   \
    T4 = __builtin_amdgcn_fmed3f(_c, _t3, _t4); }

__device__ __forceinline__ void gload16(const void* g, void* l) {
  __builtin_amdgcn_global_load_lds(
      (const __attribute__((address_space(1))) unsigned int*)g,
      (__attribute__((address_space(3))) unsigned int*)l, 16, 0, 0);
}

// ---------------- prep: normalize -> bf16 ----------------
__global__ __launch_bounds__(256) void prep_kernel(
    const float* __restrict__ x,
    __hip_bfloat16* __restrict__ abf, __hip_bfloat16* __restrict__ pbf) {
  const int w = threadIdx.x >> 6, l = threadIdx.x & 63;
  const int row = blockIdx.x * 4 + w;
  const float4* xr = (const float4*)(x + (size_t)row * 512);
  const float4 a4 = xr[l];
  const float4 p4 = xr[64 + l];
  float sa = a4.x * a4.x + a4.y * a4.y + a4.z * a4.z + a4.w * a4.w;
  float sp = p4.x * p4.x + p4.y * p4.y + p4.z * p4.z + p4.w * p4.w;
#pragma unroll
  for (int off = 32; off; off >>= 1) { sa += __shfl_xor(sa, off); sp += __shfl_xor(sp, off); }
  const float ia = 1.0f / fmaxf(sqrtf(sa), 1e-12f);
  const float ip_ = 1.0f / fmaxf(sqrtf(sp), 1e-12f);
  ushort4 ua, up;
  ua.x = __builtin_bit_cast(unsigned short, __float2bfloat16(a4.x * ia));
  ua.y = __builtin_bit_cast(unsigned short, __float2bfloat16(a4.y * ia));
  ua.z = __builtin_bit_cast(unsigned short, __float2bfloat16(a4.z * ia));
  ua.w = __builtin_bit_cast(unsigned short, __float2bfloat16(a4.w * ia));
  up.x = __builtin_bit_cast(unsigned short, __float2bfloat16(p4.x * ip_));
  up.y = __builtin_bit_cast(unsigned short, __float2bfloat16(p4.y * ip_));
  up.z = __builtin_bit_cast(unsigned short, __float2bfloat16(p4.z * ip_));
  up.w = __builtin_bit_cast(unsigned short, __float2bfloat16(p4.w * ip_));
  *(ushort4*)((char*)abf + (size_t)row * 512 + l * 8) = ua;
  *(ushort4*)((char*)pbf + (size_t)row * 512 + l * 8) = up;
}

// ---------------- dist + per-row top-5 ----------------
// grid: 4096 blocks (128 rb x 32 cb, XCD supertile), 512 thr = 8 waves;
// all waves share rows [rb*64,+64); wave wc owns cols [cb*256+wc*32,+32).
// LDS: 2 K-buffers x 20KB (A 64x32 4KB + B 256x32 16KB). Paired-row swizzle:
// logical row r, 16B-slot t -> macro-row R=r>>1, slot ((r&1)*4+t)^(R&7)
// (0 bank conflicts, R10-verified).
// mfma(bF, aF): a-row (C col) = row0+aq*16+lo;
// p-col (C row) = col0+wc*32+pq*16+hi*4+r.
__global__ __launch_bounds__(512, 4) void dist_topk_kernel(
    const __hip_bfloat16* __restrict__ abf, const __hip_bfloat16* __restrict__ pbf,
    uint32_t* __restrict__ part) {
  __shared__ __align__(16) char smem[40960]; // buf0 20KB | buf1 20KB; buf0 reused as mls

  const int tid = threadIdx.x;
  const int wc = tid >> 6, l = tid & 63;
  const int lo = l & 15, hi = l >> 4;

  // XCD supertile swizzle: per XCD 32 rb (2048 rows, 1MB A) + 16 cb (4096
  // cols, 2MB B) < 4MB L2.
  const int b = blockIdx.x;
  const int xcd = b & 7, j = b >> 3;          // j: 0..511
  const int rb = (xcd >> 1) * 32 + (j >> 4);  // 0..127 (64 rows)
  const int cb = (xcd & 1) * 16 + (j & 15);   // 0..31  (256 cols)
  const int row0 = rb * 64, col0 = cb * 256;
  const bool hasDiag = ((rb >> 2) == cb);

  f32x4 acc[4][2];
#pragma unroll
  for (int aq = 0; aq < 4; ++aq)
#pragma unroll
    for (int pq = 0; pq < 2; ++pq) { f32x4 z = {0.f, 0.f, 0.f, 0.f}; acc[aq][pq] = z; }

  // staging: linear LDS off -> R = off>>7, s = ((off>>4)&7)^(R&7),
  // row = 2R+(s>>2), kb = (s&3)*16 (inverse of the read-side swizzle).
#define STAGE(BUF, KS)                                                        \
  {                                                                           \
    if (tid < 256) {                                                          \
      const int off = tid * 16;                                               \
      const int R = off >> 7;                                                 \
      const int s = ((off >> 4) & 7) ^ (R & 7);                               \
      const int r = 2 * R + (s >> 2);                                         \
      const int kb = (s & 3) * 16;                                            \
      gload16((const char*)abf + (size_t)(row0 + r) * 512 + (KS) * 64 + kb,   \
              smem + (BUF) * 20480 + off); }                                  \
    _Pragma("unroll")                                                         \
    for (int jj = 0; jj < 2; ++jj) {                                          \
      const int off = jj * 8192 + tid * 16;                                   \
      const int R = off >> 7;                                                 \
      const int s = ((off >> 4) & 7) ^ (R & 7);                               \
      const int c = 2 * R + (s >> 2);                                         \
      const int kb = (s & 3) * 16;                                            \
      gload16((const char*)pbf + (size_t)(col0 + c) * 512 + (KS) * 64 + kb,   \
              smem + (BUF) * 20480 + 4096 + off); }                           \
  }

  // ds_read address for logical row r, slot t
#define LADDR(RR, T) (((RR) >> 1) * 128 + (((((RR) & 1) * 4 + (T)) ^ (((RR) >> 1) & 7)) * 16))

#define COMPUTE(BUF)                                                          \
  {                                                                           \
    short8 aF[4], bF0, bF1;                                                   \
    _Pragma("unroll")                                                         \
    for (int aq = 0; aq < 4; ++aq) {                                          \
      const int r = aq * 16 + lo;                                             \
      aF[aq] = *(const short8*)(smem + (BUF) * 20480 + LADDR(r, hi)); }       \
    { const int c0i = wc * 32 + lo;                                           \
      bF0 = *(const short8*)(smem + (BUF) * 20480 + 4096 + LADDR(c0i, hi)); } \
    { const int c1i = wc * 32 + 16 + lo;                                      \
      bF1 = *(const short8*)(smem + (BUF) * 20480 + 4096 + LADDR(c1i, hi)); } \
    _Pragma("unroll")                                                         \
    for (int aq = 0; aq < 4; ++aq) {                                          \
      acc[aq][0] = __builtin_amdgcn_mfma_f32_16x16x32_bf16(bF0, aF[aq], acc[aq][0], 0, 0, 0); \
      acc[aq][1] = __builtin_amdgcn_mfma_f32_16x16x32_bf16(bF1, aF[aq], acc[aq][1], 0, 0, 0); \
    }                                                                         \
  }

  // double-buffered 2-phase pipeline: stage(next) -> compute(cur) -> barrier
  STAGE(0, 0) __syncthreads();
  STAGE(1, 1) COMPUTE(0) __syncthreads();
  STAGE(0, 2) COMPUTE(1) __syncthreads();
  STAGE(1, 3) COMPUTE(0) __syncthreads();
  STAGE(0, 4) COMPUTE(1) __syncthreads();
  STAGE(1, 5) COMPUTE(0) __syncthreads();
  STAGE(0, 6) COMPUTE(1) __syncthreads();
  STAGE(1, 7) COMPUTE(0) __syncthreads();
  COMPUTE(1)

#undef STAGE
#undef LADDR
#undef COMPUTE

  // epilogue: per aq -> mine 8 keys -> cross-hi shuffle merge -> write 5 keys.
  // mls lives in buf0's region (all buf0 reads retired at the step-7 barrier;
  // the final COMPUTE(1) touches only buf1).
  uint32_t* mls = (uint32_t*)smem;            // [64][41] u32 = 10.5KB
  const int wcol = col0 + wc * 32;
  const uint32_t vbase = 8191u - (uint32_t)wcol - (uint32_t)(hi * 4);
#pragma unroll
  for (int aq = 0; aq < 4; ++aq) {
    float T0 = 0.f, T1 = 0.f, T2 = 0.f, T3 = 0.f, T4 = 0.f;
    const int arow = row0 + aq * 16 + lo;
#pragma unroll
    for (int pq = 0; pq < 2; ++pq)
#pragma unroll
      for (int r = 0; r < 4; ++r) {
        uint32_t key = (__float_as_uint(acc[aq][pq][r] + 2.0f) & 0xFFFFE000u) |
                       (vbase - (uint32_t)(pq * 16 + r));
        if (hasDiag) {
          if (wcol + pq * 16 + hi * 4 + r == arow) key = 0u;
        }
        const float c = __uint_as_float(key);
        FINS5(T0, T1, T2, T3, T4, c);
      }
    // butterfly merge across the 4 hi-groups (lanes ^16, then ^32)
#pragma unroll
    for (int rd = 0; rd < 2; ++rd) {
      const int d = 16 << rd;
      const float c0 = __shfl_xor(T0, d), c1 = __shfl_xor(T1, d),
                  c2 = __shfl_xor(T2, d), c3 = __shfl_xor(T3, d),
                  c4 = __shfl_xor(T4, d);
      FINS5(T0, T1, T2, T3, T4, c0);
      FINS5(T0, T1, T2, T3, T4, c1);
      FINS5(T0, T1, T2, T3, T4, c2);
      FINS5(T0, T1, T2, T3, T4, c3);
      FINS5(T0, T1, T2, T3, T4, c4);
    }
    if (hi == 0) {
      uint32_t* dst = mls + (aq * 16 + lo) * 41 + wc * 5;
      dst[0] = __float_as_uint(T0);
      dst[1] = __float_as_uint(T1);
      dst[2] = __float_as_uint(T2);
      dst[3] = __float_as_uint(T3);
      dst[4] = __float_as_uint(T4);
    }
  }
  __syncthreads();

  // block-level merge: 64 rows, threads 0..63 each merge 40 candidates
  if (tid < 64) {
    const uint32_t* s2 = mls + tid * 41;
    float M0 = 0.f, M1 = 0.f, M2 = 0.f, M3 = 0.f, M4 = 0.f;
#pragma unroll
    for (int k = 0; k < 40; ++k) {
      const float c = __uint_as_float(s2[k]);
      FINS5(M0, M1, M2, M3, M4, c);
    }
    const int row = row0 + tid;
    uint32_t* dst = part + ((size_t)row * NCG + cb) * 5;
    dst[0] = __float_as_uint(M0);
    dst[1] = __float_as_uint(M1);
    dst[2] = __float_as_uint(M2);
    dst[3] = __float_as_uint(M3);
    dst[4] = __float_as_uint(M4);
  }
}

// ---------------- merge splits + RNG + exact fp32 loss (4 rows/block) ----------------
__global__ __launch_bounds__(256) void merge_loss_kernel(
    const float* __restrict__ x, const uint32_t* __restrict__ part,
    float* __restrict__ rowloss,
    uint32_t k1a, uint32_t k1b, uint32_t k2a, uint32_t k2b) {
  const int w = threadIdx.x >> 6, l = threadIdx.x & 63;
  const int i = blockIdx.x * 4 + w;
  __shared__ uint32_t cs[4][160];
  const uint32_t* src = part + (size_t)i * (NCG * 5);
  cs[w][l] = src[l];
  cs[w][64 + l] = src[64 + l];
  if (l < 32) cs[w][128 + l] = src[128 + l];
  __syncthreads();

  float T0 = 0.f, T1 = 0.f, T2 = 0.f, T3 = 0.f, T4 = 0.f;
  for (int rch = 0; rch < NCG; ++rch) {
    for (int q = 0; q < 5; ++q) {      // runs sorted desc -> early out (uniform)
      const float c = __uint_as_float(cs[w][rch * 5 + q]);
      if (c <= T4) break;
      FINS5(T0, T1, T2, T3, T4, c);
    }
  }

  // RNG: coin = uniform(k1) < 0.5 <=> MSB==0 ; randint(k2,0,5)
  const uint32_t cw = rng_word(tf2x32(k1a, k1b, 0u, (uint32_t)i));
  const bool coin = (cw >> 31) == 0u;
  const uint32_t hb = rng_word(tf2x32(k2a, k2b, 0u, (uint32_t)i));
  const uint32_t lb = rng_word(tf2x32(k2a, k2b, 0u, (uint32_t)(NB + i)));
  const int rr = (int)(((hb % 5u) + (lb % 5u)) % 5u);
  const int rank = coin ? 0 : rr;
  const float kch = (rank == 0) ? T0 : (rank == 1) ? T1 : (rank == 2) ? T2
                  : (rank == 3) ? T3 : T4;
  const int neg = 8191 - (int)(__float_as_uint(kch) & 8191u);

  // exact fp32 loss from raw x
  const float4 xa = *(const float4*)(x + (size_t)i * 512 + l * 4);
  const float4 xp = *(const float4*)(x + (size_t)i * 512 + 256 + l * 4);
  const float4 xn = *(const float4*)(x + (size_t)neg * 512 + 256 + l * 4);
  float sa = xa.x * xa.x + xa.y * xa.y + xa.z * xa.z + xa.w * xa.w;
  float sp = xp.x * xp.x + xp.y * xp.y + xp.z * xp.z + xp.w * xp.w;
  float sn = xn.x * xn.x + xn.y * xn.y + xn.z * xn.z + xn.w * xn.w;
#pragma unroll
  for (int off = 32; off; off >>= 1) {
    sa += __shfl_xor(sa, off); sp += __shfl_xor(sp, off); sn += __shfl_xor(sn, off);
  }
  const float na = fmaxf(sqrtf(sa), 1e-12f);
  const float np = fmaxf(sqrtf(sp), 1e-12f);
  const float nn = fmaxf(sqrtf(sn), 1e-12f);

  float pos = 0.f, ng = 0.f;
  {
    float av, pv, nv, dp, dn;
    av = xa.x / na; pv = xp.x / np; nv = xn.x / nn;
    dp = av - pv + EPSF; pos += dp * dp; dn = av - nv + EPSF; ng += dn * dn;
    av = xa.y / na; pv = xp.y / np; nv = xn.y / nn;
    dp = av - pv + EPSF; pos += dp * dp; dn = av - nv + EPSF; ng += dn * dn;
    av = xa.z / na; pv = xp.z / np; nv = xn.z / nn;
    dp = av - pv + EPSF; pos += dp * dp; dn = av - nv + EPSF; ng += dn * dn;
    av = xa.w / na; pv = xp.w / np; nv = xn.w / nn;
    dp = av - pv + EPSF; pos += dp * dp; dn = av - nv + EPSF; ng += dn * dn;
  }
#pragma unroll
  for (int off = 32; off; off >>= 1) {
    pos += __shfl_xor(pos, off); ng += __shfl_xor(ng, off);
  }
  if (l == 0) rowloss[i] = fmaxf(pos - ng, 0.0f);
}

// ---------------- deterministic mean ----------------
__global__ __launch_bounds__(256) void finalize_kernel(
    const float* __restrict__ rowloss, float* __restrict__ out) {
  __shared__ float s[256];
  const int t = threadIdx.x;
  float a = 0.f;
  for (int k = 0; k < NB / 256; ++k) a += rowloss[t + 256 * k];
  s[t] = a;
  __syncthreads();
  for (int h = 128; h; h >>= 1) {
    if (t < h) s[t] += s[t + h];
    __syncthreads();
  }
  if (t == 0) out[0] = s[0] / (float)NB;
}

extern "C" void kernel_launch(void* const* d_in, const int* in_sizes, int n_in,
                              void* d_out, int out_size, void* d_ws, size_t ws_size,
                              hipStream_t stream) {
  (void)in_sizes; (void)n_in; (void)out_size; (void)ws_size;
  const float* x = (const float*)d_in[0];
  float* out = (float*)d_out;
  char* ws = (char*)d_ws;

  __hip_bfloat16* abf = (__hip_bfloat16*)(ws);                            // 4 MB
  __hip_bfloat16* pbf = (__hip_bfloat16*)(ws + (size_t)4 * 1024 * 1024);  // 4 MB
  uint32_t* part = (uint32_t*)(ws + (size_t)8 * 1024 * 1024);             // 5.24 MB
  float* rowloss = (float*)(ws + (size_t)8 * 1024 * 1024 +
                            (size_t)NB * NCG * 5 * sizeof(uint32_t));     // 32 KB

  // JAX: kr = key(1); k1, k2 = split(kr)  (threefry partitionable)
  U2 c0 = tf2x32(0u, 1u, 0u, 0u);
  U2 c1 = tf2x32(0u, 1u, 0u, 1u);
  const uint32_t k1a = c0.x, k1b = c0.y;
  const uint32_t k2a = c1.x, k2b = c1.y;

  prep_kernel<<<NB / 4, 256, 0, stream>>>(x, abf, pbf);
  dist_topk_kernel<<<4096, 512, 0, stream>>>(abf, pbf, part);
  merge_loss_kernel<<<NB / 4, 256, 0, stream>>>(x, part, rowloss, k1a, k1b, k2a, k2b);
  finalize_kernel<<<1, 256, 0, stream>>>(rowloss, out);
}

// Round 12
// 85.974 us; speedup vs baseline: 1.1883x; 1.1883x over previous
//
#include <hip/hip_runtime.h>
#include <hip/hip_bf16.h>
#include <stdint.h>

// B=8192 triplet loss with hard-negative mining.
// prep: normalize -> bf16
// dist_topk: single-buffer LDS GEMM (R7 schedule) repackaged: 256-thr blocks
//            (4 waves, 3 blocks/CU via launch_bounds(256,3) -> 170-reg budget,
//            no spill cliff), 128x256 tile as TWO sequential 128-col halves
//            (wave 64x64/half, acc reset between halves, NCG stays 32).
//            BK=64, 8 steps, XOR swizzle (t^(r&7)), shuffle-butterfly mining.
// merge_loss: merge 32 sorted runs (4 rows/block), JAX threefry RNG,
//             exact fp32 loss per row
// finalize: deterministic mean

#define NB 8192
#define NCG 32        // col-groups of 256
#define EPSF 1e-6f

typedef float f32x4 __attribute__((ext_vector_type(4)));
typedef short short8 __attribute__((ext_vector_type(8)));

struct U2 { uint32_t x, y; };

__host__ __device__ __forceinline__ uint32_t rotl32(uint32_t v, int n) {
  return (v << n) | (v >> (32 - n));
}

__host__ __device__ __forceinline__ U2 tf2x32(uint32_t k0, uint32_t k1,
                                              uint32_t x0, uint32_t x1) {
  uint32_t k2 = k0 ^ k1 ^ 0x1BD11BDAu;
#define TF_R(r) { x0 += x1; x1 = rotl32(x1, r); x1 ^= x0; }
  x0 += k0; x1 += k1;
  TF_R(13) TF_R(15) TF_R(26) TF_R(6)
  x0 += k1; x1 += k2 + 1u;
  TF_R(17) TF_R(29) TF_R(16) TF_R(24)
  x0 += k2; x1 += k0 + 2u;
  TF_R(13) TF_R(15) TF_R(26) TF_R(6)
  x0 += k0; x1 += k1 + 3u;
  TF_R(17) TF_R(29) TF_R(16) TF_R(24)
  x0 += k1; x1 += k2 + 4u;
  TF_R(13) TF_R(15) TF_R(26) TF_R(6)
  x0 += k2; x1 += k0 + 5u;
#undef TF_R
  U2 r; r.x = x0; r.y = x1; return r;
}

__device__ __forceinline__ uint32_t rng_word(U2 r) { return r.x ^ r.y; }

// float insertion into sorted-desc top-5 (keys are positive floats, so
// float order == u32 order); 5 independent ops.
#define FINS5(T0, T1, T2, T3, T4, C) {            \
    const float _t0 = T0, _t1 = T1, _t2 = T2, _t3 = T3, _t4 = T4, _c = C; \
    T0 = fmaxf(_t0, _c);                          \
    T1 = __builtin_amdgcn_fmed3f(_c, _t0, _t1);   \
    T2 = __builtin_amdgcn_fmed3f(_c, _t1, _t2);   \
    T3 = __builtin_amdgcn_fmed3f(_c, _t2, _t3);   \
    T4 = __builtin_amdgcn_fmed3f(_c, _t3, _t4); }

__device__ __forceinline__ void gload16(const void* g, void* l) {
  __builtin_amdgcn_global_load_lds(
      (const __attribute__((address_space(1))) unsigned int*)g,
      (__attribute__((address_space(3))) unsigned int*)l, 16, 0, 0);
}

// ---------------- prep: normalize -> bf16 ----------------
__global__ __launch_bounds__(256) void prep_kernel(
    const float* __restrict__ x,
    __hip_bfloat16* __restrict__ abf, __hip_bfloat16* __restrict__ pbf) {
  const int w = threadIdx.x >> 6, l = threadIdx.x & 63;
  const int row = blockIdx.x * 4 + w;
  const float4* xr = (const float4*)(x + (size_t)row * 512);
  const float4 a4 = xr[l];
  const float4 p4 = xr[64 + l];
  float sa = a4.x * a4.x + a4.y * a4.y + a4.z * a4.z + a4.w * a4.w;
  float sp = p4.x * p4.x + p4.y * p4.y + p4.z * p4.z + p4.w * p4.w;
#pragma unroll
  for (int off = 32; off; off >>= 1) { sa += __shfl_xor(sa, off); sp += __shfl_xor(sp, off); }
  const float ia = 1.0f / fmaxf(sqrtf(sa), 1e-12f);
  const float ip_ = 1.0f / fmaxf(sqrtf(sp), 1e-12f);
  ushort4 ua, up;
  ua.x = __builtin_bit_cast(unsigned short, __float2bfloat16(a4.x * ia));
  ua.y = __builtin_bit_cast(unsigned short, __float2bfloat16(a4.y * ia));
  ua.z = __builtin_bit_cast(unsigned short, __float2bfloat16(a4.z * ia));
  ua.w = __builtin_bit_cast(unsigned short, __float2bfloat16(a4.w * ia));
  up.x = __builtin_bit_cast(unsigned short, __float2bfloat16(p4.x * ip_));
  up.y = __builtin_bit_cast(unsigned short, __float2bfloat16(p4.y * ip_));
  up.z = __builtin_bit_cast(unsigned short, __float2bfloat16(p4.z * ip_));
  up.w = __builtin_bit_cast(unsigned short, __float2bfloat16(p4.w * ip_));
  *(ushort4*)((char*)abf + (size_t)row * 512 + l * 8) = ua;
  *(ushort4*)((char*)pbf + (size_t)row * 512 + l * 8) = up;
}

// ---------------- dist + per-row top-5 ----------------
// grid: 2048 blocks (64 rb x 32 cb, XCD supertile), 256 thr = 4 waves (wr,wc
// in {0,1}^2). Two sequential 128-col halves; per half wave owns 64x64:
// a-row (C col) = row0+wr*64+aq*16+lo; p-col (C row) = col0+h*128+wc*64+
// pq*16+hi*4+r. LDS: one 32KB buffer (A 128x64 16KB | B 128x64 16KB),
// swizzle slot t -> t^(r&7) within 128B rows; mls 10.5KB disjoint.
__global__ __launch_bounds__(256, 3) void dist_topk_kernel(
    const __hip_bfloat16* __restrict__ abf, const __hip_bfloat16* __restrict__ pbf,
    uint32_t* __restrict__ part) {
  __shared__ __align__(16) char smem[32768 + 10752];

  const int tid = threadIdx.x;
  const int w = tid >> 6, l = tid & 63;
  const int lo = l & 15, hi = l >> 4;
  const int wr = w >> 1, wc = w & 1;

  // XCD supertile swizzle: per XCD 2048 rows (1MB A) + 4096 cols (2MB B) < 4MB L2
  const int b = blockIdx.x;
  const int xcd = b & 7, j = b >> 3;          // j: 0..255
  const int rb = (xcd >> 1) * 16 + (j >> 4);  // 0..63 (128 rows)
  const int cb = (xcd & 1) * 16 + (j & 15);   // 0..31 (256 cols)
  const int row0 = rb * 128, col0 = cb * 256;
  const bool hasDiag = (cb == (rb >> 1));

  uint32_t* mls = (uint32_t*)(smem + 32768);  // [128 rows][21] u32

  f32x4 acc[4][4];

  // stage: linear LDS off -> r = off>>7, t = (off>>4)&7, slot s = t^(r&7),
  // kb = s*16 (source pre-swizzled; LDS dest linear — rule 21).
#define STAGE(H, KS)                                                          \
  {                                                                           \
    _Pragma("unroll")                                                         \
    for (int jj = 0; jj < 4; ++jj) {                                          \
      const int off = jj * 4096 + tid * 16;                                   \
      const int r = off >> 7;                                                 \
      const int kb = (((off >> 4) & 7) ^ (r & 7)) * 16;                       \
      gload16((const char*)abf + (size_t)(row0 + r) * 512 + (KS) * 128 + kb,  \
              smem + off); }                                                  \
    _Pragma("unroll")                                                         \
    for (int jj = 0; jj < 4; ++jj) {                                          \
      const int off = jj * 4096 + tid * 16;                                   \
      const int c = off >> 7;                                                 \
      const int kb = (((off >> 4) & 7) ^ (c & 7)) * 16;                       \
      gload16((const char*)pbf + (size_t)(col0 + (H) * 128 + c) * 512 +       \
                  (KS) * 128 + kb,                                            \
              smem + 16384 + off); }                                          \
  }

  // ds_read addr for logical row r, slot t: r*128 + ((t^(r&7))*16)
#define LADDR(RR, T) ((RR) * 128 + (((T) ^ ((RR) & 7)) * 16))

#define COMPUTE()                                                             \
  {                                                                           \
    _Pragma("unroll")                                                         \
    for (int kk = 0; kk < 2; ++kk) {                                          \
      short8 aF[4], bF[4];                                                    \
      _Pragma("unroll")                                                       \
      for (int aq = 0; aq < 4; ++aq) {                                        \
        const int r = wr * 64 + aq * 16 + lo;                                 \
        aF[aq] = *(const short8*)(smem + LADDR(r, kk * 4 + hi)); }            \
      _Pragma("unroll")                                                       \
      for (int pq = 0; pq < 4; ++pq) {                                        \
        const int c = wc * 64 + pq * 16 + lo;                                 \
        bF[pq] = *(const short8*)(smem + 16384 + LADDR(c, kk * 4 + hi)); }    \
      _Pragma("unroll")                                                       \
      for (int aq = 0; aq < 4; ++aq)                                          \
        _Pragma("unroll")                                                     \
        for (int pq = 0; pq < 4; ++pq)                                        \
          acc[aq][pq] = __builtin_amdgcn_mfma_f32_16x16x32_bf16(              \
              bF[pq], aF[aq], acc[aq][pq], 0, 0, 0);                          \
    }                                                                         \
  }

  // mining for half H: per aq mine 16 keys, butterfly-merge across hi, write
  // 5 keys (hi==0) to mls slot (H*2+wc). Only 5 transient regs live.
#define MINE(H)                                                               \
  {                                                                           \
    const int wcol = col0 + (H) * 128 + wc * 64;                              \
    const uint32_t vbase = 8191u - (uint32_t)wcol - (uint32_t)(hi * 4);       \
    _Pragma("unroll")                                                         \
    for (int aq = 0; aq < 4; ++aq) {                                          \
      float T0 = 0.f, T1 = 0.f, T2 = 0.f, T3 = 0.f, T4 = 0.f;                 \
      const int arow = row0 + wr * 64 + aq * 16 + lo;                         \
      _Pragma("unroll")                                                       \
      for (int pq = 0; pq < 4; ++pq)                                          \
        _Pragma("unroll")                                                     \
        for (int r = 0; r < 4; ++r) {                                         \
          uint32_t key = (__float_as_uint(acc[aq][pq][r] + 2.0f) &            \
                          0xFFFFE000u) | (vbase - (uint32_t)(pq * 16 + r));   \
          if (hasDiag) {                                                      \
            if (wcol + pq * 16 + hi * 4 + r == arow) key = 0u;                \
          }                                                                   \
          const float c = __uint_as_float(key);                               \
          FINS5(T0, T1, T2, T3, T4, c);                                       \
        }                                                                     \
      _Pragma("unroll")                                                       \
      for (int rd = 0; rd < 2; ++rd) {                                        \
        const int d = 16 << rd;                                               \
        const float c0 = __shfl_xor(T0, d), c1 = __shfl_xor(T1, d),           \
                    c2 = __shfl_xor(T2, d), c3 = __shfl_xor(T3, d),           \
                    c4 = __shfl_xor(T4, d);                                   \
        FINS5(T0, T1, T2, T3, T4, c0);                                        \
        FINS5(T0, T1, T2, T3, T4, c1);                                        \
        FINS5(T0, T1, T2, T3, T4, c2);                                        \
        FINS5(T0, T1, T2, T3, T4, c3);                                        \
        FINS5(T0, T1, T2, T3, T4, c4);                                        \
      }                                                                       \
      if (hi == 0) {                                                          \
        uint32_t* dst = mls + (wr * 64 + aq * 16 + lo) * 21 + ((H) * 2 + wc) * 5; \
        dst[0] = __float_as_uint(T0);                                         \
        dst[1] = __float_as_uint(T1);                                         \
        dst[2] = __float_as_uint(T2);                                         \
        dst[3] = __float_as_uint(T3);                                         \
        dst[4] = __float_as_uint(T4);                                         \
      }                                                                       \
    }                                                                         \
  }

#define ZACC()                                                                \
  {                                                                           \
    _Pragma("unroll")                                                         \
    for (int aq = 0; aq < 4; ++aq)                                            \
      _Pragma("unroll")                                                       \
      for (int pq = 0; pq < 4; ++pq) {                                        \
        f32x4 z = {0.f, 0.f, 0.f, 0.f}; acc[aq][pq] = z; }                    \
  }

  // half 0
  ZACC()
  STAGE(0, 0) __syncthreads(); COMPUTE();
  __syncthreads(); STAGE(0, 1) __syncthreads(); COMPUTE();
  __syncthreads(); STAGE(0, 2) __syncthreads(); COMPUTE();
  __syncthreads(); STAGE(0, 3) __syncthreads(); COMPUTE();
  MINE(0)
  // half 1
  ZACC()
  __syncthreads(); STAGE(1, 0) __syncthreads(); COMPUTE();
  __syncthreads(); STAGE(1, 1) __syncthreads(); COMPUTE();
  __syncthreads(); STAGE(1, 2) __syncthreads(); COMPUTE();
  __syncthreads(); STAGE(1, 3) __syncthreads(); COMPUTE();
  MINE(1)

#undef STAGE
#undef LADDR
#undef COMPUTE
#undef MINE
#undef ZACC

  __syncthreads();
  // block-level merge: 128 rows, threads 0..127 each merge 20 candidates
  if (tid < 128) {
    const uint32_t* s2 = mls + tid * 21;
    float M0 = 0.f, M1 = 0.f, M2 = 0.f, M3 = 0.f, M4 = 0.f;
#pragma unroll
    for (int k = 0; k < 20; ++k) {
      const float c = __uint_as_float(s2[k]);
      FINS5(M0, M1, M2, M3, M4, c);
    }
    const int row = row0 + tid;
    uint32_t* dst = part + ((size_t)row * NCG + cb) * 5;
    dst[0] = __float_as_uint(M0);
    dst[1] = __float_as_uint(M1);
    dst[2] = __float_as_uint(M2);
    dst[3] = __float_as_uint(M3);
    dst[4] = __float_as_uint(M4);
  }
}

// ---------------- merge splits + RNG + exact fp32 loss (4 rows/block) ----------------
__global__ __launch_bounds__(256) void merge_loss_kernel(
    const float* __restrict__ x, const uint32_t* __restrict__ part,
    float* __restrict__ rowloss,
    uint32_t k1a, uint32_t k1b, uint32_t k2a, uint32_t k2b) {
  const int w = threadIdx.x >> 6, l = threadIdx.x & 63;
  const int i = blockIdx.x * 4 + w;
  __shared__ uint32_t cs[4][160];
  const uint32_t* src = part + (size_t)i * (NCG * 5);
  cs[w][l] = src[l];
  cs[w][64 + l] = src[64 + l];
  if (l < 32) cs[w][128 + l] = src[128 + l];
  __syncthreads();

  float T0 = 0.f, T1 = 0.f, T2 = 0.f, T3 = 0.f, T4 = 0.f;
  for (int rch = 0; rch < NCG; ++rch) {
    for (int q = 0; q < 5; ++q) {      // runs sorted desc -> early out (uniform)
      const float c = __uint_as_float(cs[w][rch * 5 + q]);
      if (c <= T4) break;
      FINS5(T0, T1, T2, T3, T4, c);
    }
  }

  // RNG: coin = uniform(k1) < 0.5 <=> MSB==0 ; randint(k2,0,5)
  const uint32_t cw = rng_word(tf2x32(k1a, k1b, 0u, (uint32_t)i));
  const bool coin = (cw >> 31) == 0u;
  const uint32_t hb = rng_word(tf2x32(k2a, k2b, 0u, (uint32_t)i));
  const uint32_t lb = rng_word(tf2x32(k2a, k2b, 0u, (uint32_t)(NB + i)));
  const int rr = (int)(((hb % 5u) + (lb % 5u)) % 5u);
  const int rank = coin ? 0 : rr;
  const float kch = (rank == 0) ? T0 : (rank == 1) ? T1 : (rank == 2) ? T2
                  : (rank == 3) ? T3 : T4;
  const int neg = 8191 - (int)(__float_as_uint(kch) & 8191u);

  // exact fp32 loss from raw x
  const float4 xa = *(const float4*)(x + (size_t)i * 512 + l * 4);
  const float4 xp = *(const float4*)(x + (size_t)i * 512 + 256 + l * 4);
  const float4 xn = *(const float4*)(x + (size_t)neg * 512 + 256 + l * 4);
  float sa = xa.x * xa.x + xa.y * xa.y + xa.z * xa.z + xa.w * xa.w;
  float sp = xp.x * xp.x + xp.y * xp.y + xp.z * xp.z + xp.w * xp.w;
  float sn = xn.x * xn.x + xn.y * xn.y + xn.z * xn.z + xn.w * xn.w;
#pragma unroll
  for (int off = 32; off; off >>= 1) {
    sa += __shfl_xor(sa, off); sp += __shfl_xor(sp, off); sn += __shfl_xor(sn, off);
  }
  const float na = fmaxf(sqrtf(sa), 1e-12f);
  const float np = fmaxf(sqrtf(sp), 1e-12f);
  const float nn = fmaxf(sqrtf(sn), 1e-12f);

  float pos = 0.f, ng = 0.f;
  {
    float av, pv, nv, dp, dn;
    av = xa.x / na; pv = xp.x / np; nv = xn.x / nn;
    dp = av - pv + EPSF; pos += dp * dp; dn = av - nv + EPSF; ng += dn * dn;
    av = xa.y / na; pv = xp.y / np; nv = xn.y / nn;
    dp = av - pv + EPSF; pos += dp * dp; dn = av - nv + EPSF; ng += dn * dn;
    av = xa.z / na; pv = xp.z / np; nv = xn.z / nn;
    dp = av - pv + EPSF; pos += dp * dp; dn = av - nv + EPSF; ng += dn * dn;
    av = xa.w / na; pv = xp.w / np; nv = xn.w / nn;
    dp = av - pv + EPSF; pos += dp * dp; dn = av - nv + EPSF; ng += dn * dn;
  }
#pragma unroll
  for (int off = 32; off; off >>= 1) {
    pos += __shfl_xor(pos, off); ng += __shfl_xor(ng, off);
  }
  if (l == 0) rowloss[i] = fmaxf(pos - ng, 0.0f);
}

// ---------------- deterministic mean ----------------
__global__ __launch_bounds__(256) void finalize_kernel(
    const float* __restrict__ rowloss, float* __restrict__ out) {
  __shared__ float s[256];
  const int t = threadIdx.x;
  float a = 0.f;
  for (int k = 0; k < NB / 256; ++k) a += rowloss[t + 256 * k];
  s[t] = a;
  __syncthreads();
  for (int h = 128; h; h >>= 1) {
    if (t < h) s[t] += s[t + h];
    __syncthreads();
  }
  if (t == 0) out[0] = s[0] / (float)NB;
}

extern "C" void kernel_launch(void* const* d_in, const int* in_sizes, int n_in,
                              void* d_out, int out_size, void* d_ws, size_t ws_size,
                              hipStream_t stream) {
  (void)in_sizes; (void)n_in; (void)out_size; (void)ws_size;
  const float* x = (const float*)d_in[0];
  float* out = (float*)d_out;
  char* ws = (char*)d_ws;

  __hip_bfloat16* abf = (__hip_bfloat16*)(ws);                            // 4 MB
  __hip_bfloat16* pbf = (__hip_bfloat16*)(ws + (size_t)4 * 1024 * 1024);  // 4 MB
  uint32_t* part = (uint32_t*)(ws + (size_t)8 * 1024 * 1024);             // 5.24 MB
  float* rowloss = (float*)(ws + (size_t)8 * 1024 * 1024 +
                            (size_t)NB * NCG * 5 * sizeof(uint32_t));     // 32 KB

  // JAX: kr = key(1); k1, k2 = split(kr)  (threefry partitionable)
  U2 c0 = tf2x32(0u, 1u, 0u, 0u);
  U2 c1 = tf2x32(0u, 1u, 0u, 1u);
  const uint32_t k1a = c0.x, k1b = c0.y;
  const uint32_t k2a = c1.x, k2b = c1.y;

  prep_kernel<<<NB / 4, 256, 0, stream>>>(x, abf, pbf);
  dist_topk_kernel<<<2048, 256, 0, stream>>>(abf, pbf, part);
  merge_loss_kernel<<<NB / 4, 256, 0, stream>>>(x, part, rowloss, k1a, k1b, k2a, k2b);
  finalize_kernel<<<1, 256, 0, stream>>>(rowloss, out);
}

// Round 13
// 78.388 us; speedup vs baseline: 1.3033x; 1.0968x over previous
//
#include <hip/hip_runtime.h>
#include <hip/hip_bf16.h>
#include <stdint.h>

// B=8192 triplet loss with hard-negative mining.
// prep: normalize -> bf16
// dist_topk: counted-vmcnt double-buffered GEMM (T3/T4). 128x256 tile, BK=32,
//            8 K-steps, 8 waves (2x4 of 64x64), 2x24KB LDS. Per step:
//            STAGE(next) -> s_waitcnt vmcnt(3) -> s_barrier -> COMPUTE ->
//            s_barrier. vmcnt never drains to 0 in-loop (loads ride across
//            barriers). (512,2) launch bounds: ~256-reg budget -> no spill
//            (R8-R12 all spilled under tight budgets). Paired-row swizzle
//            (0 conflicts, R10). Butterfly-shuffle mining (R11/R12).
// merge_loss: merge 32 sorted runs (4 rows/block), JAX threefry RNG,
//             exact fp32 loss per row
// finalize: deterministic mean

#define NB 8192
#define NCG 32        // col-groups of 256
#define EPSF 1e-6f

typedef float f32x4 __attribute__((ext_vector_type(4)));
typedef short short8 __attribute__((ext_vector_type(8)));

struct U2 { uint32_t x, y; };

__host__ __device__ __forceinline__ uint32_t rotl32(uint32_t v, int n) {
  return (v << n) | (v >> (32 - n));
}

__host__ __device__ __forceinline__ U2 tf2x32(uint32_t k0, uint32_t k1,
                                              uint32_t x0, uint32_t x1) {
  uint32_t k2 = k0 ^ k1 ^ 0x1BD11BDAu;
#define TF_R(r) { x0 += x1; x1 = rotl32(x1, r); x1 ^= x0; }
  x0 += k0; x1 += k1;
  TF_R(13) TF_R(15) TF_R(26) TF_R(6)
  x0 += k1; x1 += k2 + 1u;
  TF_R(17) TF_R(29) TF_R(16) TF_R(24)
  x0 += k2; x1 += k0 + 2u;
  TF_R(13) TF_R(15) TF_R(26) TF_R(6)
  x0 += k0; x1 += k1 + 3u;
  TF_R(17) TF_R(29) TF_R(16) TF_R(24)
  x0 += k1; x1 += k2 + 4u;
  TF_R(13) TF_R(15) TF_R(26) TF_R(6)
  x0 += k2; x1 += k0 + 5u;
#undef TF_R
  U2 r; r.x = x0; r.y = x1; return r;
}

__device__ __forceinline__ uint32_t rng_word(U2 r) { return r.x ^ r.y; }

// float insertion into sorted-desc top-5 (keys are positive floats, so
// float order == u32 order); 5 independent ops.
#define FINS5(T0, T1, T2, T3, T4, C) {            \
    const float _t0 = T0, _t1 = T1, _t2 = T2, _t3 = T3, _t4 = T4, _c = C; \
    T0 = fmaxf(_t0, _c);                          \
    T1 = __builtin_amdgcn_fmed3f(_c, _t0, _t1);   \
    T2 = __builtin_amdgcn_fmed3f(_c, _t1, _t2);   \
    T3 = __builtin_amdgcn_fmed3f(_c, _t2, _t3);   \
    T4 = __builtin_amdgcn_fmed3f(_c, _t3, _t4); }

__device__ __forceinline__ void gload16(const void* g, void* l) {
  __builtin_amdgcn_global_load_lds(
      (const __attribute__((address_space(1))) unsigned int*)g,
      (__attribute__((address_space(3))) unsigned int*)l, 16, 0, 0);
}

// ---------------- prep: normalize -> bf16 ----------------
__global__ __launch_bounds__(256) void prep_kernel(
    const float* __restrict__ x,
    __hip_bfloat16* __restrict__ abf, __hip_bfloat16* __restrict__ pbf) {
  const int w = threadIdx.x >> 6, l = threadIdx.x & 63;
  const int row = blockIdx.x * 4 + w;
  const float4* xr = (const float4*)(x + (size_t)row * 512);
  const float4 a4 = xr[l];
  const float4 p4 = xr[64 + l];
  float sa = a4.x * a4.x + a4.y * a4.y + a4.z * a4.z + a4.w * a4.w;
  float sp = p4.x * p4.x + p4.y * p4.y + p4.z * p4.z + p4.w * p4.w;
#pragma unroll
  for (int off = 32; off; off >>= 1) { sa += __shfl_xor(sa, off); sp += __shfl_xor(sp, off); }
  const float ia = 1.0f / fmaxf(sqrtf(sa), 1e-12f);
  const float ip_ = 1.0f / fmaxf(sqrtf(sp), 1e-12f);
  ushort4 ua, up;
  ua.x = __builtin_bit_cast(unsigned short, __float2bfloat16(a4.x * ia));
  ua.y = __builtin_bit_cast(unsigned short, __float2bfloat16(a4.y * ia));
  ua.z = __builtin_bit_cast(unsigned short, __float2bfloat16(a4.z * ia));
  ua.w = __builtin_bit_cast(unsigned short, __float2bfloat16(a4.w * ia));
  up.x = __builtin_bit_cast(unsigned short, __float2bfloat16(p4.x * ip_));
  up.y = __builtin_bit_cast(unsigned short, __float2bfloat16(p4.y * ip_));
  up.z = __builtin_bit_cast(unsigned short, __float2bfloat16(p4.z * ip_));
  up.w = __builtin_bit_cast(unsigned short, __float2bfloat16(p4.w * ip_));
  *(ushort4*)((char*)abf + (size_t)row * 512 + l * 8) = ua;
  *(ushort4*)((char*)pbf + (size_t)row * 512 + l * 8) = up;
}

// ---------------- dist + per-row top-5 ----------------
// grid: 2048 blocks (64 rb x 32 cb, XCD supertile), 512 thr = 8 waves (2x4);
// wave (wr,wc) owns a-rows [rb*128+wr*64,+64) x p-cols [cb*256+wc*64,+64).
// LDS: 2 K-buffers x 24KB (A 128x32 8KB + B 256x32 16KB). Paired-row swizzle
// (R10, 0 conflicts): logical row r, slot t -> macro-row R=r>>1, slot
// ((r&1)*4+t)^(R&7). Counted-vmcnt pipeline, raw barriers.
// mfma(bF, aF): a-row (C col) = row0+wr*64+aq*16+lo;
// p-col (C row) = col0+wc*64+pq*16+hi*4+r.
__global__ __launch_bounds__(512, 2) void dist_topk_kernel(
    const __hip_bfloat16* __restrict__ abf, const __hip_bfloat16* __restrict__ pbf,
    uint32_t* __restrict__ part) {
  __shared__ __align__(16) char smem[49152]; // buf0 24KB | buf1 24KB; buf0 reused as mls

  const int tid = threadIdx.x;
  const int w = tid >> 6, l = tid & 63;
  const int lo = l & 15, hi = l >> 4;
  const int wr = w >> 2, wc = w & 3;

  // XCD supertile swizzle: per XCD 2048 rows (1MB A) + 4096 cols (2MB B) < 4MB L2
  const int b = blockIdx.x;
  const int xcd = b & 7, j = b >> 3;          // j: 0..255
  const int rb = (xcd >> 1) * 16 + (j >> 4);  // 0..63 (128 rows)
  const int cb = (xcd & 1) * 16 + (j & 15);   // 0..31 (256 cols)
  const int row0 = rb * 128, col0 = cb * 256;
  const bool hasDiag = (cb == (rb >> 1));

  f32x4 acc[4][4];
#pragma unroll
  for (int aq = 0; aq < 4; ++aq)
#pragma unroll
    for (int pq = 0; pq < 4; ++pq) { f32x4 z = {0.f, 0.f, 0.f, 0.f}; acc[aq][pq] = z; }

  // STAGE: 3 gload16/thread. Linear LDS dest; global source pre-swizzled
  // (inverse paired-row): off -> R=off>>7, s=((off>>4)&7)^(R&7),
  // row=2R+(s>>2), kb=(s&3)*16.
#define STAGE(BUF, KS)                                                        \
  {                                                                           \
    { const int off = tid * 16;                                               \
      const int R = off >> 7;                                                 \
      const int s = ((off >> 4) & 7) ^ (R & 7);                               \
      const int r = 2 * R + (s >> 2);                                         \
      const int kb = (s & 3) * 16;                                            \
      gload16((const char*)abf + (size_t)(row0 + r) * 512 + (KS) * 64 + kb,   \
              smem + (BUF) * 24576 + off); }                                  \
    _Pragma("unroll")                                                         \
    for (int jj = 0; jj < 2; ++jj) {                                          \
      const int off = jj * 8192 + tid * 16;                                   \
      const int R = off >> 7;                                                 \
      const int s = ((off >> 4) & 7) ^ (R & 7);                               \
      const int c = 2 * R + (s >> 2);                                         \
      const int kb = (s & 3) * 16;                                            \
      gload16((const char*)pbf + (size_t)(col0 + c) * 512 + (KS) * 64 + kb,   \
              smem + (BUF) * 24576 + 4096 * 2 + off); }                       \
  }

  // ds_read addr for logical row r, slot t (paired-row swizzle)
#define LADDR(RR, T) (((RR) >> 1) * 128 + (((((RR) & 1) * 4 + (T)) ^ (((RR) >> 1) & 7)) * 16))

#define COMPUTE(BUF)                                                          \
  {                                                                           \
    short8 aF[4], bF[4];                                                      \
    _Pragma("unroll")                                                         \
    for (int aq = 0; aq < 4; ++aq) {                                          \
      const int r = wr * 64 + aq * 16 + lo;                                   \
      aF[aq] = *(const short8*)(smem + (BUF) * 24576 + LADDR(r, hi)); }       \
    _Pragma("unroll")                                                         \
    for (int pq = 0; pq < 4; ++pq) {                                          \
      const int c = wc * 64 + pq * 16 + lo;                                   \
      bF[pq] = *(const short8*)(smem + (BUF) * 24576 + 8192 + LADDR(c, hi)); }\
    _Pragma("unroll")                                                         \
    for (int aq = 0; aq < 4; ++aq)                                            \
      _Pragma("unroll")                                                       \
      for (int pq = 0; pq < 4; ++pq)                                          \
        acc[aq][pq] = __builtin_amdgcn_mfma_f32_16x16x32_bf16(                \
            bF[pq], aF[aq], acc[aq][pq], 0, 0, 0);                            \
  }

#define WAITV3 { asm volatile("s_waitcnt vmcnt(3)" ::: "memory"); }
#define WAITV0 { asm volatile("s_waitcnt vmcnt(0)" ::: "memory"); }
#define BAR    { __builtin_amdgcn_s_barrier(); __builtin_amdgcn_sched_barrier(0); }

  // counted-vmcnt pipeline: STAGE(next) -> wait(3) -> bar -> COMPUTE -> bar.
  // Loads for step k+1 stay in flight across COMPUTE(k) (never drain to 0).
  STAGE(0, 0)
  STAGE(1, 1) WAITV3 BAR COMPUTE(0) BAR   // s=0
  STAGE(0, 2) WAITV3 BAR COMPUTE(1) BAR   // s=1
  STAGE(1, 3) WAITV3 BAR COMPUTE(0) BAR   // s=2
  STAGE(0, 4) WAITV3 BAR COMPUTE(1) BAR   // s=3
  STAGE(1, 5) WAITV3 BAR COMPUTE(0) BAR   // s=4
  STAGE(0, 6) WAITV3 BAR COMPUTE(1) BAR   // s=5
  STAGE(1, 7) WAITV3 BAR COMPUTE(0) BAR   // s=6
  WAITV0 BAR COMPUTE(1)                   // s=7

#undef STAGE
#undef LADDR
#undef COMPUTE
#undef WAITV3
#undef WAITV0
#undef BAR

  // epilogue: per aq -> mine 16 keys -> cross-hi butterfly merge -> 5 keys.
  // mls lives in buf0 (last read at s=6; s=7 touches only buf1).
  uint32_t* mls = (uint32_t*)smem;            // [128 rows][21] u32 = 10.75KB
  const uint32_t vbase = 8191u - (uint32_t)(col0 + wc * 64) - (uint32_t)(hi * 4);
#pragma unroll
  for (int aq = 0; aq < 4; ++aq) {
    float T0 = 0.f, T1 = 0.f, T2 = 0.f, T3 = 0.f, T4 = 0.f;
    const int arow = row0 + wr * 64 + aq * 16 + lo;
#pragma unroll
    for (int pq = 0; pq < 4; ++pq)
#pragma unroll
      for (int r = 0; r < 4; ++r) {
        uint32_t key = (__float_as_uint(acc[aq][pq][r] + 2.0f) & 0xFFFFE000u) |
                       (vbase - (uint32_t)(pq * 16 + r));
        if (hasDiag) {
          if (col0 + wc * 64 + pq * 16 + hi * 4 + r == arow) key = 0u;
        }
        const float c = __uint_as_float(key);
        FINS5(T0, T1, T2, T3, T4, c);
      }
    // butterfly merge across the 4 hi-groups (lanes ^16, then ^32)
#pragma unroll
    for (int rd = 0; rd < 2; ++rd) {
      const int d = 16 << rd;
      const float c0 = __shfl_xor(T0, d), c1 = __shfl_xor(T1, d),
                  c2 = __shfl_xor(T2, d), c3 = __shfl_xor(T3, d),
                  c4 = __shfl_xor(T4, d);
      FINS5(T0, T1, T2, T3, T4, c0);
      FINS5(T0, T1, T2, T3, T4, c1);
      FINS5(T0, T1, T2, T3, T4, c2);
      FINS5(T0, T1, T2, T3, T4, c3);
      FINS5(T0, T1, T2, T3, T4, c4);
    }
    if (hi == 0) {
      uint32_t* dst = mls + (wr * 64 + aq * 16 + lo) * 21 + wc * 5;
      dst[0] = __float_as_uint(T0);
      dst[1] = __float_as_uint(T1);
      dst[2] = __float_as_uint(T2);
      dst[3] = __float_as_uint(T3);
      dst[4] = __float_as_uint(T4);
    }
  }
  __syncthreads();

  // block-level merge: 128 rows, threads 0..127 each merge 20 candidates
  if (tid < 128) {
    const uint32_t* s2 = mls + tid * 21;
    float M0 = 0.f, M1 = 0.f, M2 = 0.f, M3 = 0.f, M4 = 0.f;
#pragma unroll
    for (int k = 0; k < 20; ++k) {
      const float c = __uint_as_float(s2[k]);
      FINS5(M0, M1, M2, M3, M4, c);
    }
    const int row = row0 + tid;
    uint32_t* dst = part + ((size_t)row * NCG + cb) * 5;
    dst[0] = __float_as_uint(M0);
    dst[1] = __float_as_uint(M1);
    dst[2] = __float_as_uint(M2);
    dst[3] = __float_as_uint(M3);
    dst[4] = __float_as_uint(M4);
  }
}

// ---------------- merge splits + RNG + exact fp32 loss (4 rows/block) ----------------
__global__ __launch_bounds__(256) void merge_loss_kernel(
    const float* __restrict__ x, const uint32_t* __restrict__ part,
    float* __restrict__ rowloss,
    uint32_t k1a, uint32_t k1b, uint32_t k2a, uint32_t k2b) {
  const int w = threadIdx.x >> 6, l = threadIdx.x & 63;
  const int i = blockIdx.x * 4 + w;
  __shared__ uint32_t cs[4][160];
  const uint32_t* src = part + (size_t)i * (NCG * 5);
  cs[w][l] = src[l];
  cs[w][64 + l] = src[64 + l];
  if (l < 32) cs[w][128 + l] = src[128 + l];
  __syncthreads();

  float T0 = 0.f, T1 = 0.f, T2 = 0.f, T3 = 0.f, T4 = 0.f;
  for (int rch = 0; rch < NCG; ++rch) {
    for (int q = 0; q < 5; ++q) {      // runs sorted desc -> early out (uniform)
      const float c = __uint_as_float(cs[w][rch * 5 + q]);
      if (c <= T4) break;
      FINS5(T0, T1, T2, T3, T4, c);
    }
  }

  // RNG: coin = uniform(k1) < 0.5 <=> MSB==0 ; randint(k2,0,5)
  const uint32_t cw = rng_word(tf2x32(k1a, k1b, 0u, (uint32_t)i));
  const bool coin = (cw >> 31) == 0u;
  const uint32_t hb = rng_word(tf2x32(k2a, k2b, 0u, (uint32_t)i));
  const uint32_t lb = rng_word(tf2x32(k2a, k2b, 0u, (uint32_t)(NB + i)));
  const int rr = (int)(((hb % 5u) + (lb % 5u)) % 5u);
  const int rank = coin ? 0 : rr;
  const float kch = (rank == 0) ? T0 : (rank == 1) ? T1 : (rank == 2) ? T2
                  : (rank == 3) ? T3 : T4;
  const int neg = 8191 - (int)(__float_as_uint(kch) & 8191u);

  // exact fp32 loss from raw x
  const float4 xa = *(const float4*)(x + (size_t)i * 512 + l * 4);
  const float4 xp = *(const float4*)(x + (size_t)i * 512 + 256 + l * 4);
  const float4 xn = *(const float4*)(x + (size_t)neg * 512 + 256 + l * 4);
  float sa = xa.x * xa.x + xa.y * xa.y + xa.z * xa.z + xa.w * xa.w;
  float sp = xp.x * xp.x + xp.y * xp.y + xp.z * xp.z + xp.w * xp.w;
  float sn = xn.x * xn.x + xn.y * xn.y + xn.z * xn.z + xn.w * xn.w;
#pragma unroll
  for (int off = 32; off; off >>= 1) {
    sa += __shfl_xor(sa, off); sp += __shfl_xor(sp, off); sn += __shfl_xor(sn, off);
  }
  const float na = fmaxf(sqrtf(sa), 1e-12f);
  const float np = fmaxf(sqrtf(sp), 1e-12f);
  const float nn = fmaxf(sqrtf(sn), 1e-12f);

  float pos = 0.f, ng = 0.f;
  {
    float av, pv, nv, dp, dn;
    av = xa.x / na; pv = xp.x / np; nv = xn.x / nn;
    dp = av - pv + EPSF; pos += dp * dp; dn = av - nv + EPSF; ng += dn * dn;
    av = xa.y / na; pv = xp.y / np; nv = xn.y / nn;
    dp = av - pv + EPSF; pos += dp * dp; dn = av - nv + EPSF; ng += dn * dn;
    av = xa.z / na; pv = xp.z / np; nv = xn.z / nn;
    dp = av - pv + EPSF; pos += dp * dp; dn = av - nv + EPSF; ng += dn * dn;
    av = xa.w / na; pv = xp.w / np; nv = xn.w / nn;
    dp = av - pv + EPSF; pos += dp * dp; dn = av - nv + EPSF; ng += dn * dn;
  }
#pragma unroll
  for (int off = 32; off; off >>= 1) {
    pos += __shfl_xor(pos, off); ng += __shfl_xor(ng, off);
  }
  if (l == 0) rowloss[i] = fmaxf(pos - ng, 0.0f);
}

// ---------------- deterministic mean ----------------
__global__ __launch_bounds__(256) void finalize_kernel(
    const float* __restrict__ rowloss, float* __restrict__ out) {
  __shared__ float s[256];
  const int t = threadIdx.x;
  float a = 0.f;
  for (int k = 0; k < NB / 256; ++k) a += rowloss[t + 256 * k];
  s[t] = a;
  __syncthreads();
  for (int h = 128; h; h >>= 1) {
    if (t < h) s[t] += s[t + h];
    __syncthreads();
  }
  if (t == 0) out[0] = s[0] / (float)NB;
}

extern "C" void kernel_launch(void* const* d_in, const int* in_sizes, int n_in,
                              void* d_out, int out_size, void* d_ws, size_t ws_size,
                              hipStream_t stream) {
  (void)in_sizes; (void)n_in; (void)out_size; (void)ws_size;
  const float* x = (const float*)d_in[0];
  float* out = (float*)d_out;
  char* ws = (char*)d_ws;

  __hip_bfloat16* abf = (__hip_bfloat16*)(ws);                            // 4 MB
  __hip_bfloat16* pbf = (__hip_bfloat16*)(ws + (size_t)4 * 1024 * 1024);  // 4 MB
  uint32_t* part = (uint32_t*)(ws + (size_t)8 * 1024 * 1024);             // 5.24 MB
  float* rowloss = (float*)(ws + (size_t)8 * 1024 * 1024 +
                            (size_t)NB * NCG * 5 * sizeof(uint32_t));     // 32 KB

  // JAX: kr = key(1); k1, k2 = split(kr)  (threefry partitionable)
  U2 c0 = tf2x32(0u, 1u, 0u, 0u);
  U2 c1 = tf2x32(0u, 1u, 0u, 1u);
  const uint32_t k1a = c0.x, k1b = c0.y;
  const uint32_t k2a = c1.x, k2b = c1.y;

  prep_kernel<<<NB / 4, 256, 0, stream>>>(x, abf, pbf);
  dist_topk_kernel<<<2048, 512, 0, stream>>>(abf, pbf, part);
  merge_loss_kernel<<<NB / 4, 256, 0, stream>>>(x, part, rowloss, k1a, k1b, k2a, k2b);
  finalize_kernel<<<1, 256, 0, stream>>>(rowloss, out);
}

// Round 14
// 75.096 us; speedup vs baseline: 1.3604x; 1.0438x over previous
//
#include <hip/hip_runtime.h>
#include <hip/hip_bf16.h>
#include <stdint.h>

// B=8192 triplet loss with hard-negative mining.
// prep: normalize -> bf16
// dist_topk: counted-vmcnt dbuf GEMM, 128x256 tile, BK=32, 8 waves (2x4 of
//            64x64). COMPUTE internally interleaves ds_read and MFMA (T3 fine
//            interleave); setprio(1) around MFMA clusters (T5); no
//            sched_barrier (memory clobbers suffice). Paired-row swizzle
//            (0 conflicts). Epilogue: per-lane top-5 -> mls[128][81] ->
//            256-thread pair-merge (no butterfly; -40% epilogue VALU).
// merge_loss: merge 32 sorted runs (4 rows/block), JAX threefry RNG,
//             exact fp32 loss per row
// finalize: deterministic mean

#define NB 8192
#define NCG 32        // col-groups of 256
#define EPSF 1e-6f

typedef float f32x4 __attribute__((ext_vector_type(4)));
typedef short short8 __attribute__((ext_vector_type(8)));

struct U2 { uint32_t x, y; };

__host__ __device__ __forceinline__ uint32_t rotl32(uint32_t v, int n) {
  return (v << n) | (v >> (32 - n));
}

__host__ __device__ __forceinline__ U2 tf2x32(uint32_t k0, uint32_t k1,
                                              uint32_t x0, uint32_t x1) {
  uint32_t k2 = k0 ^ k1 ^ 0x1BD11BDAu;
#define TF_R(r) { x0 += x1; x1 = rotl32(x1, r); x1 ^= x0; }
  x0 += k0; x1 += k1;
  TF_R(13) TF_R(15) TF_R(26) TF_R(6)
  x0 += k1; x1 += k2 + 1u;
  TF_R(17) TF_R(29) TF_R(16) TF_R(24)
  x0 += k2; x1 += k0 + 2u;
  TF_R(13) TF_R(15) TF_R(26) TF_R(6)
  x0 += k0; x1 += k1 + 3u;
  TF_R(17) TF_R(29) TF_R(16) TF_R(24)
  x0 += k1; x1 += k2 + 4u;
  TF_R(13) TF_R(15) TF_R(26) TF_R(6)
  x0 += k2; x1 += k0 + 5u;
#undef TF_R
  U2 r; r.x = x0; r.y = x1; return r;
}

__device__ __forceinline__ uint32_t rng_word(U2 r) { return r.x ^ r.y; }

// float insertion into sorted-desc top-5 (keys are positive floats, so
// float order == u32 order); 5 independent ops.
#define FINS5(T0, T1, T2, T3, T4, C) {            \
    const float _t0 = T0, _t1 = T1, _t2 = T2, _t3 = T3, _t4 = T4, _c = C; \
    T0 = fmaxf(_t0, _c);                          \
    T1 = __builtin_amdgcn_fmed3f(_c, _t0, _t1);   \
    T2 = __builtin_amdgcn_fmed3f(_c, _t1, _t2);   \
    T3 = __builtin_amdgcn_fmed3f(_c, _t2, _t3);   \
    T4 = __builtin_amdgcn_fmed3f(_c, _t3, _t4); }

__device__ __forceinline__ void gload16(const void* g, void* l) {
  __builtin_amdgcn_global_load_lds(
      (const __attribute__((address_space(1))) unsigned int*)g,
      (__attribute__((address_space(3))) unsigned int*)l, 16, 0, 0);
}

// ---------------- prep: normalize -> bf16 ----------------
__global__ __launch_bounds__(256) void prep_kernel(
    const float* __restrict__ x,
    __hip_bfloat16* __restrict__ abf, __hip_bfloat16* __restrict__ pbf) {
  const int w = threadIdx.x >> 6, l = threadIdx.x & 63;
  const int row = blockIdx.x * 4 + w;
  const float4* xr = (const float4*)(x + (size_t)row * 512);
  const float4 a4 = xr[l];
  const float4 p4 = xr[64 + l];
  float sa = a4.x * a4.x + a4.y * a4.y + a4.z * a4.z + a4.w * a4.w;
  float sp = p4.x * p4.x + p4.y * p4.y + p4.z * p4.z + p4.w * p4.w;
#pragma unroll
  for (int off = 32; off; off >>= 1) { sa += __shfl_xor(sa, off); sp += __shfl_xor(sp, off); }
  const float ia = 1.0f / fmaxf(sqrtf(sa), 1e-12f);
  const float ip_ = 1.0f / fmaxf(sqrtf(sp), 1e-12f);
  ushort4 ua, up;
  ua.x = __builtin_bit_cast(unsigned short, __float2bfloat16(a4.x * ia));
  ua.y = __builtin_bit_cast(unsigned short, __float2bfloat16(a4.y * ia));
  ua.z = __builtin_bit_cast(unsigned short, __float2bfloat16(a4.z * ia));
  ua.w = __builtin_bit_cast(unsigned short, __float2bfloat16(a4.w * ia));
  up.x = __builtin_bit_cast(unsigned short, __float2bfloat16(p4.x * ip_));
  up.y = __builtin_bit_cast(unsigned short, __float2bfloat16(p4.y * ip_));
  up.z = __builtin_bit_cast(unsigned short, __float2bfloat16(p4.z * ip_));
  up.w = __builtin_bit_cast(unsigned short, __float2bfloat16(p4.w * ip_));
  *(ushort4*)((char*)abf + (size_t)row * 512 + l * 8) = ua;
  *(ushort4*)((char*)pbf + (size_t)row * 512 + l * 8) = up;
}

// ---------------- dist + per-row top-5 ----------------
// grid: 2048 blocks (64 rb x 32 cb, XCD supertile), 512 thr = 8 waves (2x4);
// wave (wr,wc) owns a-rows [rb*128+wr*64,+64) x p-cols [cb*256+wc*64,+64).
// LDS: 2 K-buffers x 24KB (A 128x32 8KB + B 256x32 16KB). Paired-row swizzle
// (0 conflicts): logical row r, slot t -> macro-row R=r>>1, slot
// ((r&1)*4+t)^(R&7). Counted-vmcnt pipeline, raw barriers, setprio on MFMA.
// mfma(bF, aF): a-row (C col) = row0+wr*64+aq*16+lo;
// p-col (C row) = col0+wc*64+pq*16+hi*4+r.
__global__ __launch_bounds__(512, 2) void dist_topk_kernel(
    const __hip_bfloat16* __restrict__ abf, const __hip_bfloat16* __restrict__ pbf,
    uint32_t* __restrict__ part) {
  __shared__ __align__(16) char smem[49152]; // buf0|buf1; reused as mls[128][81]

  const int tid = threadIdx.x;
  const int w = tid >> 6, l = tid & 63;
  const int lo = l & 15, hi = l >> 4;
  const int wr = w >> 2, wc = w & 3;

  // XCD supertile swizzle: per XCD 2048 rows (1MB A) + 4096 cols (2MB B) < 4MB L2
  const int b = blockIdx.x;
  const int xcd = b & 7, j = b >> 3;          // j: 0..255
  const int rb = (xcd >> 1) * 16 + (j >> 4);  // 0..63 (128 rows)
  const int cb = (xcd & 1) * 16 + (j & 15);   // 0..31 (256 cols)
  const int row0 = rb * 128, col0 = cb * 256;
  const bool hasDiag = (cb == (rb >> 1));

  f32x4 acc[4][4];
#pragma unroll
  for (int aq = 0; aq < 4; ++aq)
#pragma unroll
    for (int pq = 0; pq < 4; ++pq) { f32x4 z = {0.f, 0.f, 0.f, 0.f}; acc[aq][pq] = z; }

  // STAGE: 3 gload16/thread. Linear LDS dest; global source pre-swizzled
  // (inverse paired-row): off -> R=off>>7, s=((off>>4)&7)^(R&7),
  // row=2R+(s>>2), kb=(s&3)*16.
#define STAGE(BUF, KS)                                                        \
  {                                                                           \
    { const int off = tid * 16;                                               \
      const int R = off >> 7;                                                 \
      const int s = ((off >> 4) & 7) ^ (R & 7);                               \
      const int r = 2 * R + (s >> 2);                                         \
      const int kb = (s & 3) * 16;                                            \
      gload16((const char*)abf + (size_t)(row0 + r) * 512 + (KS) * 64 + kb,   \
              smem + (BUF) * 24576 + off); }                                  \
    _Pragma("unroll")                                                         \
    for (int jj = 0; jj < 2; ++jj) {                                          \
      const int off = jj * 8192 + tid * 16;                                   \
      const int R = off >> 7;                                                 \
      const int s = ((off >> 4) & 7) ^ (R & 7);                               \
      const int c = 2 * R + (s >> 2);                                         \
      const int kb = (s & 3) * 16;                                            \
      gload16((const char*)pbf + (size_t)(col0 + c) * 512 + (KS) * 64 + kb,   \
              smem + (BUF) * 24576 + 8192 + off); }                           \
  }

  // ds_read addr for logical row r, slot t (paired-row swizzle)
#define LADDR(RR, T) (((RR) >> 1) * 128 + (((((RR) & 1) * 4 + (T)) ^ (((RR) >> 1) & 7)) * 16))

  // COMPUTE: ds_read / MFMA interleaved so LDS and MFMA pipes overlap across
  // waves (T3 fine interleave); setprio(1) keeps MFMA-entering waves favored.
#define COMPUTE(BUF)                                                          \
  {                                                                           \
    short8 aF0, aF1, aF2, aF3, bF0, bF1, bF2, bF3;                            \
    { const int r = wr * 64 + 0 + lo;                                         \
      aF0 = *(const short8*)(smem + (BUF) * 24576 + LADDR(r, hi)); }          \
    { const int r = wr * 64 + 16 + lo;                                        \
      aF1 = *(const short8*)(smem + (BUF) * 24576 + LADDR(r, hi)); }          \
    { const int r = wr * 64 + 32 + lo;                                        \
      aF2 = *(const short8*)(smem + (BUF) * 24576 + LADDR(r, hi)); }          \
    { const int r = wr * 64 + 48 + lo;                                        \
      aF3 = *(const short8*)(smem + (BUF) * 24576 + LADDR(r, hi)); }          \
    { const int c = wc * 64 + 0 + lo;                                         \
      bF0 = *(const short8*)(smem + (BUF) * 24576 + 8192 + LADDR(c, hi)); }   \
    { const int c = wc * 64 + 16 + lo;                                        \
      bF1 = *(const short8*)(smem + (BUF) * 24576 + 8192 + LADDR(c, hi)); }   \
    __builtin_amdgcn_s_setprio(1);                                            \
    acc[0][0] = __builtin_amdgcn_mfma_f32_16x16x32_bf16(bF0, aF0, acc[0][0], 0, 0, 0); \
    acc[1][0] = __builtin_amdgcn_mfma_f32_16x16x32_bf16(bF0, aF1, acc[1][0], 0, 0, 0); \
    acc[2][0] = __builtin_amdgcn_mfma_f32_16x16x32_bf16(bF0, aF2, acc[2][0], 0, 0, 0); \
    acc[3][0] = __builtin_amdgcn_mfma_f32_16x16x32_bf16(bF0, aF3, acc[3][0], 0, 0, 0); \
    { const int c = wc * 64 + 32 + lo;                                        \
      bF2 = *(const short8*)(smem + (BUF) * 24576 + 8192 + LADDR(c, hi)); }   \
    acc[0][1] = __builtin_amdgcn_mfma_f32_16x16x32_bf16(bF1, aF0, acc[0][1], 0, 0, 0); \
    acc[1][1] = __builtin_amdgcn_mfma_f32_16x16x32_bf16(bF1, aF1, acc[1][1], 0, 0, 0); \
    acc[2][1] = __builtin_amdgcn_mfma_f32_16x16x32_bf16(bF1, aF2, acc[2][1], 0, 0, 0); \
    acc[3][1] = __builtin_amdgcn_mfma_f32_16x16x32_bf16(bF1, aF3, acc[3][1], 0, 0, 0); \
    { const int c = wc * 64 + 48 + lo;                                        \
      bF3 = *(const short8*)(smem + (BUF) * 24576 + 8192 + LADDR(c, hi)); }   \
    acc[0][2] = __builtin_amdgcn_mfma_f32_16x16x32_bf16(bF2, aF0, acc[0][2], 0, 0, 0); \
    acc[1][2] = __builtin_amdgcn_mfma_f32_16x16x32_bf16(bF2, aF1, acc[1][2], 0, 0, 0); \
    acc[2][2] = __builtin_amdgcn_mfma_f32_16x16x32_bf16(bF2, aF2, acc[2][2], 0, 0, 0); \
    acc[3][2] = __builtin_amdgcn_mfma_f32_16x16x32_bf16(bF2, aF3, acc[3][2], 0, 0, 0); \
    acc[0][3] = __builtin_amdgcn_mfma_f32_16x16x32_bf16(bF3, aF0, acc[0][3], 0, 0, 0); \
    acc[1][3] = __builtin_amdgcn_mfma_f32_16x16x32_bf16(bF3, aF1, acc[1][3], 0, 0, 0); \
    acc[2][3] = __builtin_amdgcn_mfma_f32_16x16x32_bf16(bF3, aF2, acc[2][3], 0, 0, 0); \
    acc[3][3] = __builtin_amdgcn_mfma_f32_16x16x32_bf16(bF3, aF3, acc[3][3], 0, 0, 0); \
    __builtin_amdgcn_s_setprio(0);                                            \
  }

#define WAITV3 { asm volatile("s_waitcnt vmcnt(3)" ::: "memory"); }
#define WAITV0 { asm volatile("s_waitcnt vmcnt(0)" ::: "memory"); }
#define BAR    { __builtin_amdgcn_s_barrier(); }

  // counted-vmcnt pipeline: STAGE(next) -> wait(3) -> bar -> COMPUTE -> bar.
  STAGE(0, 0)
  STAGE(1, 1) WAITV3 BAR COMPUTE(0) BAR   // s=0
  STAGE(0, 2) WAITV3 BAR COMPUTE(1) BAR   // s=1
  STAGE(1, 3) WAITV3 BAR COMPUTE(0) BAR   // s=2
  STAGE(0, 4) WAITV3 BAR COMPUTE(1) BAR   // s=3
  STAGE(1, 5) WAITV3 BAR COMPUTE(0) BAR   // s=4
  STAGE(0, 6) WAITV3 BAR COMPUTE(1) BAR   // s=5
  STAGE(1, 7) WAITV3 BAR COMPUTE(0) BAR   // s=6
  WAITV0 BAR COMPUTE(1)                   // s=7

#undef STAGE
#undef LADDR
#undef COMPUTE
#undef WAITV3
#undef WAITV0
#undef BAR

  // epilogue: all buf reads must retire before mls overwrites buf0+buf1.
  __syncthreads();
  uint32_t* mls = (uint32_t*)smem;            // [128 rows][81] u32 = 41.5KB
  const uint32_t vbase = 8191u - (uint32_t)(col0 + wc * 64) - (uint32_t)(hi * 4);
#pragma unroll
  for (int aq = 0; aq < 4; ++aq) {
    float T0 = 0.f, T1 = 0.f, T2 = 0.f, T3 = 0.f, T4 = 0.f;
    const int arow = row0 + wr * 64 + aq * 16 + lo;
#pragma unroll
    for (int pq = 0; pq < 4; ++pq)
#pragma unroll
      for (int r = 0; r < 4; ++r) {
        uint32_t key = (__float_as_uint(acc[aq][pq][r] + 2.0f) & 0xFFFFE000u) |
                       (vbase - (uint32_t)(pq * 16 + r));
        if (hasDiag) {
          if (col0 + wc * 64 + pq * 16 + hi * 4 + r == arow) key = 0u;
        }
        const float c = __uint_as_float(key);
        FINS5(T0, T1, T2, T3, T4, c);
      }
    uint32_t* dst = mls + (wr * 64 + aq * 16 + lo) * 81 + (wc * 4 + hi) * 5;
    dst[0] = __float_as_uint(T0);
    dst[1] = __float_as_uint(T1);
    dst[2] = __float_as_uint(T2);
    dst[3] = __float_as_uint(T3);
    dst[4] = __float_as_uint(T4);
  }
  __syncthreads();

  // block-level merge: 2 threads/row x 40 keys, then shfl_xor(1) pair-merge
  if (tid < 256) {
    const int row = tid >> 1, half = tid & 1;
    const uint32_t* s2 = mls + row * 81 + half * 40;
    float M0 = 0.f, M1 = 0.f, M2 = 0.f, M3 = 0.f, M4 = 0.f;
#pragma unroll
    for (int k = 0; k < 40; ++k) {
      const float c = __uint_as_float(s2[k]);
      FINS5(M0, M1, M2, M3, M4, c);
    }
    const float c0 = __shfl_xor(M0, 1), c1 = __shfl_xor(M1, 1),
                c2 = __shfl_xor(M2, 1), c3 = __shfl_xor(M3, 1),
                c4 = __shfl_xor(M4, 1);
    FINS5(M0, M1, M2, M3, M4, c0);
    FINS5(M0, M1, M2, M3, M4, c1);
    FINS5(M0, M1, M2, M3, M4, c2);
    FINS5(M0, M1, M2, M3, M4, c3);
    FINS5(M0, M1, M2, M3, M4, c4);
    if (half == 0) {
      uint32_t* dst = part + ((size_t)(row0 + row) * NCG + cb) * 5;
      dst[0] = __float_as_uint(M0);
      dst[1] = __float_as_uint(M1);
      dst[2] = __float_as_uint(M2);
      dst[3] = __float_as_uint(M3);
      dst[4] = __float_as_uint(M4);
    }
  }
}

// ---------------- merge splits + RNG + exact fp32 loss (4 rows/block) ----------------
__global__ __launch_bounds__(256) void merge_loss_kernel(
    const float* __restrict__ x, const uint32_t* __restrict__ part,
    float* __restrict__ rowloss,
    uint32_t k1a, uint32_t k1b, uint32_t k2a, uint32_t k2b) {
  const int w = threadIdx.x >> 6, l = threadIdx.x & 63;
  const int i = blockIdx.x * 4 + w;
  __shared__ uint32_t cs[4][160];
  const uint32_t* src = part + (size_t)i * (NCG * 5);
  cs[w][l] = src[l];
  cs[w][64 + l] = src[64 + l];
  if (l < 32) cs[w][128 + l] = src[128 + l];
  __syncthreads();

  float T0 = 0.f, T1 = 0.f, T2 = 0.f, T3 = 0.f, T4 = 0.f;
  for (int rch = 0; rch < NCG; ++rch) {
    for (int q = 0; q < 5; ++q) {      // runs sorted desc -> early out (uniform)
      const float c = __uint_as_float(cs[w][rch * 5 + q]);
      if (c <= T4) break;
      FINS5(T0, T1, T2, T3, T4, c);
    }
  }

  // RNG: coin = uniform(k1) < 0.5 <=> MSB==0 ; randint(k2,0,5)
  const uint32_t cw = rng_word(tf2x32(k1a, k1b, 0u, (uint32_t)i));
  const bool coin = (cw >> 31) == 0u;
  const uint32_t hb = rng_word(tf2x32(k2a, k2b, 0u, (uint32_t)i));
  const uint32_t lb = rng_word(tf2x32(k2a, k2b, 0u, (uint32_t)(NB + i)));
  const int rr = (int)(((hb % 5u) + (lb % 5u)) % 5u);
  const int rank = coin ? 0 : rr;
  const float kch = (rank == 0) ? T0 : (rank == 1) ? T1 : (rank == 2) ? T2
                  : (rank == 3) ? T3 : T4;
  const int neg = 8191 - (int)(__float_as_uint(kch) & 8191u);

  // exact fp32 loss from raw x
  const float4 xa = *(const float4*)(x + (size_t)i * 512 + l * 4);
  const float4 xp = *(const float4*)(x + (size_t)i * 512 + 256 + l * 4);
  const float4 xn = *(const float4*)(x + (size_t)neg * 512 + 256 + l * 4);
  float sa = xa.x * xa.x + xa.y * xa.y + xa.z * xa.z + xa.w * xa.w;
  float sp = xp.x * xp.x + xp.y * xp.y + xp.z * xp.z + xp.w * xp.w;
  float sn = xn.x * xn.x + xn.y * xn.y + xn.z * xn.z + xn.w * xn.w;
#pragma unroll
  for (int off = 32; off; off >>= 1) {
    sa += __shfl_xor(sa, off); sp += __shfl_xor(sp, off); sn += __shfl_xor(sn, off);
  }
  const float na = fmaxf(sqrtf(sa), 1e-12f);
  const float np = fmaxf(sqrtf(sp), 1e-12f);
  const float nn = fmaxf(sqrtf(sn), 1e-12f);

  float pos = 0.f, ng = 0.f;
  {
    float av, pv, nv, dp, dn;
    av = xa.x / na; pv = xp.x / np; nv = xn.x / nn;
    dp = av - pv + EPSF; pos += dp * dp; dn = av - nv + EPSF; ng += dn * dn;
    av = xa.y / na; pv = xp.y / np; nv = xn.y / nn;
    dp = av - pv + EPSF; pos += dp * dp; dn = av - nv + EPSF; ng += dn * dn;
    av = xa.z / na; pv = xp.z / np; nv = xn.z / nn;
    dp = av - pv + EPSF; pos += dp * dp; dn = av - nv + EPSF; ng += dn * dn;
    av = xa.w / na; pv = xp.w / np; nv = xn.w / nn;
    dp = av - pv + EPSF; pos += dp * dp; dn = av - nv + EPSF; ng += dn * dn;
  }
#pragma unroll
  for (int off = 32; off; off >>= 1) {
    pos += __shfl_xor(pos, off); ng += __shfl_xor(ng, off);
  }
  if (l == 0) rowloss[i] = fmaxf(pos - ng, 0.0f);
}

// ---------------- deterministic mean ----------------
__global__ __launch_bounds__(256) void finalize_kernel(
    const float* __restrict__ rowloss, float* __restrict__ out) {
  __shared__ float s[256];
  const int t = threadIdx.x;
  float a = 0.f;
  for (int k = 0; k < NB / 256; ++k) a += rowloss[t + 256 * k];
  s[t] = a;
  __syncthreads();
  for (int h = 128; h; h >>= 1) {
    if (t < h) s[t] += s[t + h];
    __syncthreads();
  }
  if (t == 0) out[0] = s[0] / (float)NB;
}

extern "C" void kernel_launch(void* const* d_in, const int* in_sizes, int n_in,
                              void* d_out, int out_size, void* d_ws, size_t ws_size,
                              hipStream_t stream) {
  (void)in_sizes; (void)n_in; (void)out_size; (void)ws_size;
  const float* x = (const float*)d_in[0];
  float* out = (float*)d_out;
  char* ws = (char*)d_ws;

  __hip_bfloat16* abf = (__hip_bfloat16*)(ws);                            // 4 MB
  __hip_bfloat16* pbf = (__hip_bfloat16*)(ws + (size_t)4 * 1024 * 1024);  // 4 MB
  uint32_t* part = (uint32_t*)(ws + (size_t)8 * 1024 * 1024);             // 5.24 MB
  float* rowloss = (float*)(ws + (size_t)8 * 1024 * 1024 +
                            (size_t)NB * NCG * 5 * sizeof(uint32_t));     // 32 KB

  // JAX: kr = key(1); k1, k2 = split(kr)  (threefry partitionable)
  U2 c0 = tf2x32(0u, 1u, 0u, 0u);
  U2 c1 = tf2x32(0u, 1u, 0u, 1u);
  const uint32_t k1a = c0.x, k1b = c0.y;
  const uint32_t k2a = c1.x, k2b = c1.y;

  prep_kernel<<<NB / 4, 256, 0, stream>>>(x, abf, pbf);
  dist_topk_kernel<<<2048, 512, 0, stream>>>(abf, pbf, part);
  merge_loss_kernel<<<NB / 4, 256, 0, stream>>>(x, part, rowloss, k1a, k1b, k2a, k2b);
  finalize_kernel<<<1, 256, 0, stream>>>(rowloss, out);
}

// Round 15
// 63.765 us; speedup vs baseline: 1.6022x; 1.1777x over previous
//
#include <hip/hip_runtime.h>
#include <hip/hip_bf16.h>
#include <stdint.h>

// B=8192 triplet loss with hard-negative mining.
// prep: normalize -> int8 (x127). Mining needs only SELECTION precision;
//       i8 MFMA is exact on quantized values (noise ~3e-3 on ip vs 9e-3
//       budget); loss still computed exactly from fp32 x.
// dist_topk: counted-vmcnt dbuf GEMM, 128x256 tile, BK=64 (i8 K=64 MFMA ->
//            4 K-steps: MFMA, LDS bytes, barriers all HALVED vs bf16).
//            Paired-row swizzle (0 conflicts). Fine ds_read/MFMA interleave
//            + setprio. Epilogue: per-lane top-5 keys -> mls[128][81] ->
//            2-thread/row merge.
// merge_loss: merge 32 sorted runs (4 rows/block), JAX threefry RNG,
//             exact fp32 loss per row
// finalize: deterministic mean

#define NB 8192
#define NCG 32        // col-groups of 256
#define EPSF 1e-6f

typedef int i32x4 __attribute__((ext_vector_type(4)));

struct U2 { uint32_t x, y; };

__host__ __device__ __forceinline__ uint32_t rotl32(uint32_t v, int n) {
  return (v << n) | (v >> (32 - n));
}

__host__ __device__ __forceinline__ U2 tf2x32(uint32_t k0, uint32_t k1,
                                              uint32_t x0, uint32_t x1) {
  uint32_t k2 = k0 ^ k1 ^ 0x1BD11BDAu;
#define TF_R(r) { x0 += x1; x1 = rotl32(x1, r); x1 ^= x0; }
  x0 += k0; x1 += k1;
  TF_R(13) TF_R(15) TF_R(26) TF_R(6)
  x0 += k1; x1 += k2 + 1u;
  TF_R(17) TF_R(29) TF_R(16) TF_R(24)
  x0 += k2; x1 += k0 + 2u;
  TF_R(13) TF_R(15) TF_R(26) TF_R(6)
  x0 += k0; x1 += k1 + 3u;
  TF_R(17) TF_R(29) TF_R(16) TF_R(24)
  x0 += k1; x1 += k2 + 4u;
  TF_R(13) TF_R(15) TF_R(26) TF_R(6)
  x0 += k2; x1 += k0 + 5u;
#undef TF_R
  U2 r; r.x = x0; r.y = x1; return r;
}

__device__ __forceinline__ uint32_t rng_word(U2 r) { return r.x ^ r.y; }

// float insertion into sorted-desc top-5 (keys are positive normal floats,
// so float order == u32 order); 5 independent ops.
#define FINS5(T0, T1, T2, T3, T4, C) {            \
    const float _t0 = T0, _t1 = T1, _t2 = T2, _t3 = T3, _t4 = T4, _c = C; \
    T0 = fmaxf(_t0, _c);                          \
    T1 = __builtin_amdgcn_fmed3f(_c, _t0, _t1);   \
    T2 = __builtin_amdgcn_fmed3f(_c, _t1, _t2);   \
    T3 = __builtin_amdgcn_fmed3f(_c, _t2, _t3);   \
    T4 = __builtin_amdgcn_fmed3f(_c, _t3, _t4); }

__device__ __forceinline__ void gload16(const void* g, void* l) {
  __builtin_amdgcn_global_load_lds(
      (const __attribute__((address_space(1))) unsigned int*)g,
      (__attribute__((address_space(3))) unsigned int*)l, 16, 0, 0);
}

// ---------------- prep: normalize -> int8 (x127) ----------------
__global__ __launch_bounds__(256) void prep_kernel(
    const float* __restrict__ x,
    char* __restrict__ aq8, char* __restrict__ pq8) {
  const int w = threadIdx.x >> 6, l = threadIdx.x & 63;
  const int row = blockIdx.x * 4 + w;
  const float4* xr = (const float4*)(x + (size_t)row * 512);
  const float4 a4 = xr[l];
  const float4 p4 = xr[64 + l];
  float sa = a4.x * a4.x + a4.y * a4.y + a4.z * a4.z + a4.w * a4.w;
  float sp = p4.x * p4.x + p4.y * p4.y + p4.z * p4.z + p4.w * p4.w;
#pragma unroll
  for (int off = 32; off; off >>= 1) { sa += __shfl_xor(sa, off); sp += __shfl_xor(sp, off); }
  const float ia = 127.0f / fmaxf(sqrtf(sa), 1e-12f);
  const float ip_ = 127.0f / fmaxf(sqrtf(sp), 1e-12f);
  const int qa0 = (int)rintf(a4.x * ia), qa1 = (int)rintf(a4.y * ia);
  const int qa2 = (int)rintf(a4.z * ia), qa3 = (int)rintf(a4.w * ia);
  const int qp0 = (int)rintf(p4.x * ip_), qp1 = (int)rintf(p4.y * ip_);
  const int qp2 = (int)rintf(p4.z * ip_), qp3 = (int)rintf(p4.w * ip_);
  const uint32_t ua = (qa0 & 255) | ((qa1 & 255) << 8) |
                      ((qa2 & 255) << 16) | ((uint32_t)(qa3 & 255) << 24);
  const uint32_t up = (qp0 & 255) | ((qp1 & 255) << 8) |
                      ((qp2 & 255) << 16) | ((uint32_t)(qp3 & 255) << 24);
  *(uint32_t*)(aq8 + (size_t)row * 256 + l * 4) = ua;
  *(uint32_t*)(pq8 + (size_t)row * 256 + l * 4) = up;
}

// ---------------- dist + per-row top-5 (i8) ----------------
// grid: 2048 blocks (64 rb x 32 cb, XCD supertile), 512 thr = 8 waves (2x4);
// wave (wr,wc) owns a-rows [rb*128+wr*64,+64) x p-cols [cb*256+wc*64,+64).
// LDS: 2 K-buffers x 24KB (A 128x64B 8KB + B 256x64B 16KB). Paired-row
// swizzle (0 conflicts): logical row r (64B), slot t -> macro-row R=r>>1,
// slot ((r&1)*4+t)^(R&7). 4 K-steps of BK=64 (mfma_i32_16x16x64_i8).
// mfma(bF, aF): a-row (C col) = row0+wr*64+aq*16+lo;
// p-col (C row) = col0+wc*64+pq*16+hi*4+r.
__global__ __launch_bounds__(512, 2) void dist_topk_kernel(
    const char* __restrict__ aq8, const char* __restrict__ pq8,
    uint32_t* __restrict__ part) {
  __shared__ __align__(16) char smem[49152]; // buf0|buf1; reused as mls[128][81]

  const int tid = threadIdx.x;
  const int w = tid >> 6, l = tid & 63;
  const int lo = l & 15, hi = l >> 4;
  const int wr = w >> 2, wc = w & 3;

  // XCD supertile swizzle: per XCD 2048 rows (0.5MB A) + 4096 cols (1MB B) < L2
  const int b = blockIdx.x;
  const int xcd = b & 7, j = b >> 3;          // j: 0..255
  const int rb = (xcd >> 1) * 16 + (j >> 4);  // 0..63 (128 rows)
  const int cb = (xcd & 1) * 16 + (j & 15);   // 0..31 (256 cols)
  const int row0 = rb * 128, col0 = cb * 256;
  const bool hasDiag = (cb == (rb >> 1));

  i32x4 acc[4][4];
#pragma unroll
  for (int aq = 0; aq < 4; ++aq)
#pragma unroll
    for (int pq = 0; pq < 4; ++pq) { i32x4 z = {0, 0, 0, 0}; acc[aq][pq] = z; }

  // STAGE: 3 gload16/thread. Linear LDS dest; global source pre-swizzled
  // (inverse paired-row): off -> R=off>>7, s=((off>>4)&7)^(R&7),
  // row=2R+(s>>2), kb=(s&3)*16. i8 row stride 256B; K-step stride 64B.
#define STAGE(BUF, KS)                                                        \
  {                                                                           \
    { const int off = tid * 16;                                               \
      const int R = off >> 7;                                                 \
      const int s = ((off >> 4) & 7) ^ (R & 7);                               \
      const int r = 2 * R + (s >> 2);                                         \
      const int kb = (s & 3) * 16;                                            \
      gload16(aq8 + (size_t)(row0 + r) * 256 + (KS) * 64 + kb,                \
              smem + (BUF) * 24576 + off); }                                  \
    _Pragma("unroll")                                                         \
    for (int jj = 0; jj < 2; ++jj) {                                          \
      const int off = jj * 8192 + tid * 16;                                   \
      const int R = off >> 7;                                                 \
      const int s = ((off >> 4) & 7) ^ (R & 7);                               \
      const int c = 2 * R + (s >> 2);                                         \
      const int kb = (s & 3) * 16;                                            \
      gload16(pq8 + (size_t)(col0 + c) * 256 + (KS) * 64 + kb,                \
              smem + (BUF) * 24576 + 8192 + off); }                           \
  }

  // ds_read addr for logical row r (64B), slot t (paired-row swizzle)
#define LADDR(RR, T) (((RR) >> 1) * 128 + (((((RR) & 1) * 4 + (T)) ^ (((RR) >> 1) & 7)) * 16))

  // COMPUTE: 8 ds_read_b128 + 16 MFMA, fine-interleaved; setprio on MFMA.
#define COMPUTE(BUF)                                                          \
  {                                                                           \
    i32x4 aF0, aF1, aF2, aF3, bF0, bF1, bF2, bF3;                             \
    { const int r = wr * 64 + 0 + lo;                                         \
      aF0 = __builtin_bit_cast(i32x4, *(const uint4*)(smem + (BUF) * 24576 + LADDR(r, hi))); } \
    { const int r = wr * 64 + 16 + lo;                                        \
      aF1 = __builtin_bit_cast(i32x4, *(const uint4*)(smem + (BUF) * 24576 + LADDR(r, hi))); } \
    { const int r = wr * 64 + 32 + lo;                                        \
      aF2 = __builtin_bit_cast(i32x4, *(const uint4*)(smem + (BUF) * 24576 + LADDR(r, hi))); } \
    { const int r = wr * 64 + 48 + lo;                                        \
      aF3 = __builtin_bit_cast(i32x4, *(const uint4*)(smem + (BUF) * 24576 + LADDR(r, hi))); } \
    { const int c = wc * 64 + 0 + lo;                                         \
      bF0 = __builtin_bit_cast(i32x4, *(const uint4*)(smem + (BUF) * 24576 + 8192 + LADDR(c, hi))); } \
    { const int c = wc * 64 + 16 + lo;                                        \
      bF1 = __builtin_bit_cast(i32x4, *(const uint4*)(smem + (BUF) * 24576 + 8192 + LADDR(c, hi))); } \
    __builtin_amdgcn_s_setprio(1);                                            \
    acc[0][0] = __builtin_amdgcn_mfma_i32_16x16x64_i8(bF0, aF0, acc[0][0], 0, 0, 0); \
    acc[1][0] = __builtin_amdgcn_mfma_i32_16x16x64_i8(bF0, aF1, acc[1][0], 0, 0, 0); \
    acc[2][0] = __builtin_amdgcn_mfma_i32_16x16x64_i8(bF0, aF2, acc[2][0], 0, 0, 0); \
    acc[3][0] = __builtin_amdgcn_mfma_i32_16x16x64_i8(bF0, aF3, acc[3][0], 0, 0, 0); \
    { const int c = wc * 64 + 32 + lo;                                        \
      bF2 = __builtin_bit_cast(i32x4, *(const uint4*)(smem + (BUF) * 24576 + 8192 + LADDR(c, hi))); } \
    acc[0][1] = __builtin_amdgcn_mfma_i32_16x16x64_i8(bF1, aF0, acc[0][1], 0, 0, 0); \
    acc[1][1] = __builtin_amdgcn_mfma_i32_16x16x64_i8(bF1, aF1, acc[1][1], 0, 0, 0); \
    acc[2][1] = __builtin_amdgcn_mfma_i32_16x16x64_i8(bF1, aF2, acc[2][1], 0, 0, 0); \
    acc[3][1] = __builtin_amdgcn_mfma_i32_16x16x64_i8(bF1, aF3, acc[3][1], 0, 0, 0); \
    { const int c = wc * 64 + 48 + lo;                                        \
      bF3 = __builtin_bit_cast(i32x4, *(const uint4*)(smem + (BUF) * 24576 + 8192 + LADDR(c, hi))); } \
    acc[0][2] = __builtin_amdgcn_mfma_i32_16x16x64_i8(bF2, aF0, acc[0][2], 0, 0, 0); \
    acc[1][2] = __builtin_amdgcn_mfma_i32_16x16x64_i8(bF2, aF1, acc[1][2], 0, 0, 0); \
    acc[2][2] = __builtin_amdgcn_mfma_i32_16x16x64_i8(bF2, aF2, acc[2][2], 0, 0, 0); \
    acc[3][2] = __builtin_amdgcn_mfma_i32_16x16x64_i8(bF2, aF3, acc[3][2], 0, 0, 0); \
    acc[0][3] = __builtin_amdgcn_mfma_i32_16x16x64_i8(bF3, aF0, acc[0][3], 0, 0, 0); \
    acc[1][3] = __builtin_amdgcn_mfma_i32_16x16x64_i8(bF3, aF1, acc[1][3], 0, 0, 0); \
    acc[2][3] = __builtin_amdgcn_mfma_i32_16x16x64_i8(bF3, aF2, acc[2][3], 0, 0, 0); \
    acc[3][3] = __builtin_amdgcn_mfma_i32_16x16x64_i8(bF3, aF3, acc[3][3], 0, 0, 0); \
    __builtin_amdgcn_s_setprio(0);                                            \
  }

#define WAITV3 { asm volatile("s_waitcnt vmcnt(3)" ::: "memory"); }
#define WAITV0 { asm volatile("s_waitcnt vmcnt(0)" ::: "memory"); }
#define BAR    { __builtin_amdgcn_s_barrier(); }

  // counted-vmcnt pipeline, 4 K-steps of 64
  STAGE(0, 0)
  STAGE(1, 1) WAITV3 BAR COMPUTE(0) BAR   // s=0
  STAGE(0, 2) WAITV3 BAR COMPUTE(1) BAR   // s=1
  STAGE(1, 3) WAITV3 BAR COMPUTE(0) BAR   // s=2
  WAITV0 BAR COMPUTE(1)                   // s=3

#undef STAGE
#undef LADDR
#undef COMPUTE
#undef WAITV3
#undef WAITV0
#undef BAR

  // epilogue: all buf reads must retire before mls overwrites the buffers.
  __syncthreads();
  uint32_t* mls = (uint32_t*)smem;            // [128 rows][81] u32 = 41.5KB
  const uint32_t vbase = 8191u - (uint32_t)(col0 + wc * 64) - (uint32_t)(hi * 4);
  const float SC = 1.0f / 16129.0f;           // 1/(127*127): int ip -> cosine
#pragma unroll
  for (int aq = 0; aq < 4; ++aq) {
    float T0 = 0.f, T1 = 0.f, T2 = 0.f, T3 = 0.f, T4 = 0.f;
    const int arow = row0 + wr * 64 + aq * 16 + lo;
#pragma unroll
    for (int pq = 0; pq < 4; ++pq)
#pragma unroll
      for (int r = 0; r < 4; ++r) {
        const float f = fmaf((float)acc[aq][pq][r], SC, 2.0f); // in [1.74,2.26]
        uint32_t key = (__float_as_uint(f) & 0xFFFFE000u) |
                       (vbase - (uint32_t)(pq * 16 + r));
        if (hasDiag) {
          if (col0 + wc * 64 + pq * 16 + hi * 4 + r == arow) key = 0u;
        }
        const float c = __uint_as_float(key);
        FINS5(T0, T1, T2, T3, T4, c);
      }
    uint32_t* dst = mls + (wr * 64 + aq * 16 + lo) * 81 + (wc * 4 + hi) * 5;
    dst[0] = __float_as_uint(T0);
    dst[1] = __float_as_uint(T1);
    dst[2] = __float_as_uint(T2);
    dst[3] = __float_as_uint(T3);
    dst[4] = __float_as_uint(T4);
  }
  __syncthreads();

  // block-level merge: 2 threads/row x 40 keys, then shfl_xor(1) pair-merge
  if (tid < 256) {
    const int row = tid >> 1, half = tid & 1;
    const uint32_t* s2 = mls + row * 81 + half * 40;
    float M0 = 0.f, M1 = 0.f, M2 = 0.f, M3 = 0.f, M4 = 0.f;
#pragma unroll
    for (int k = 0; k < 40; ++k) {
      const float c = __uint_as_float(s2[k]);
      FINS5(M0, M1, M2, M3, M4, c);
    }
    const float c0 = __shfl_xor(M0, 1), c1 = __shfl_xor(M1, 1),
                c2 = __shfl_xor(M2, 1), c3 = __shfl_xor(M3, 1),
                c4 = __shfl_xor(M4, 1);
    FINS5(M0, M1, M2, M3, M4, c0);
    FINS5(M0, M1, M2, M3, M4, c1);
    FINS5(M0, M1, M2, M3, M4, c2);
    FINS5(M0, M1, M2, M3, M4, c3);
    FINS5(M0, M1, M2, M3, M4, c4);
    if (half == 0) {
      uint32_t* dst = part + ((size_t)(row0 + row) * NCG + cb) * 5;
      dst[0] = __float_as_uint(M0);
      dst[1] = __float_as_uint(M1);
      dst[2] = __float_as_uint(M2);
      dst[3] = __float_as_uint(M3);
      dst[4] = __float_as_uint(M4);
    }
  }
}

// ---------------- merge splits + RNG + exact fp32 loss (4 rows/block) ----------------
__global__ __launch_bounds__(256) void merge_loss_kernel(
    const float* __restrict__ x, const uint32_t* __restrict__ part,
    float* __restrict__ rowloss,
    uint32_t k1a, uint32_t k1b, uint32_t k2a, uint32_t k2b) {
  const int w = threadIdx.x >> 6, l = threadIdx.x & 63;
  const int i = blockIdx.x * 4 + w;
  __shared__ uint32_t cs[4][160];
  const uint32_t* src = part + (size_t)i * (NCG * 5);
  cs[w][l] = src[l];
  cs[w][64 + l] = src[64 + l];
  if (l < 32) cs[w][128 + l] = src[128 + l];
  __syncthreads();

  float T0 = 0.f, T1 = 0.f, T2 = 0.f, T3 = 0.f, T4 = 0.f;
  for (int rch = 0; rch < NCG; ++rch) {
    for (int q = 0; q < 5; ++q) {      // runs sorted desc -> early out (uniform)
      const float c = __uint_as_float(cs[w][rch * 5 + q]);
      if (c <= T4) break;
      FINS5(T0, T1, T2, T3, T4, c);
    }
  }

  // RNG: coin = uniform(k1) < 0.5 <=> MSB==0 ; randint(k2,0,5)
  const uint32_t cw = rng_word(tf2x32(k1a, k1b, 0u, (uint32_t)i));
  const bool coin = (cw >> 31) == 0u;
  const uint32_t hb = rng_word(tf2x32(k2a, k2b, 0u, (uint32_t)i));
  const uint32_t lb = rng_word(tf2x32(k2a, k2b, 0u, (uint32_t)(NB + i)));
  const int rr = (int)(((hb % 5u) + (lb % 5u)) % 5u);
  const int rank = coin ? 0 : rr;
  const float kch = (rank == 0) ? T0 : (rank == 1) ? T1 : (rank == 2) ? T2
                  : (rank == 3) ? T3 : T4;
  const int neg = 8191 - (int)(__float_as_uint(kch) & 8191u);

  // exact fp32 loss from raw x
  const float4 xa = *(const float4*)(x + (size_t)i * 512 + l * 4);
  const float4 xp = *(const float4*)(x + (size_t)i * 512 + 256 + l * 4);
  const float4 xn = *(const float4*)(x + (size_t)neg * 512 + 256 + l * 4);
  float sa = xa.x * xa.x + xa.y * xa.y + xa.z * xa.z + xa.w * xa.w;
  float sp = xp.x * xp.x + xp.y * xp.y + xp.z * xp.z + xp.w * xp.w;
  float sn = xn.x * xn.x + xn.y * xn.y + xn.z * xn.z + xn.w * xn.w;
#pragma unroll
  for (int off = 32; off; off >>= 1) {
    sa += __shfl_xor(sa, off); sp += __shfl_xor(sp, off); sn += __shfl_xor(sn, off);
  }
  const float na = fmaxf(sqrtf(sa), 1e-12f);
  const float np = fmaxf(sqrtf(sp), 1e-12f);
  const float nn = fmaxf(sqrtf(sn), 1e-12f);

  float pos = 0.f, ng = 0.f;
  {
    float av, pv, nv, dp, dn;
    av = xa.x / na; pv = xp.x / np; nv = xn.x / nn;
    dp = av - pv + EPSF; pos += dp * dp; dn = av - nv + EPSF; ng += dn * dn;
    av = xa.y / na; pv = xp.y / np; nv = xn.y / nn;
    dp = av - pv + EPSF; pos += dp * dp; dn = av - nv + EPSF; ng += dn * dn;
    av = xa.z / na; pv = xp.z / np; nv = xn.z / nn;
    dp = av - pv + EPSF; pos += dp * dp; dn = av - nv + EPSF; ng += dn * dn;
    av = xa.w / na; pv = xp.w / np; nv = xn.w / nn;
    dp = av - pv + EPSF; pos += dp * dp; dn = av - nv + EPSF; ng += dn * dn;
  }
#pragma unroll
  for (int off = 32; off; off >>= 1) {
    pos += __shfl_xor(pos, off); ng += __shfl_xor(ng, off);
  }
  if (l == 0) rowloss[i] = fmaxf(pos - ng, 0.0f);
}

// ---------------- deterministic mean ----------------
__global__ __launch_bounds__(256) void finalize_kernel(
    const float* __restrict__ rowloss, float* __restrict__ out) {
  __shared__ float s[256];
  const int t = threadIdx.x;
  float a = 0.f;
  for (int k = 0; k < NB / 256; ++k) a += rowloss[t + 256 * k];
  s[t] = a;
  __syncthreads();
  for (int h = 128; h; h >>= 1) {
    if (t < h) s[t] += s[t + h];
    __syncthreads();
  }
  if (t == 0) out[0] = s[0] / (float)NB;
}

extern "C" void kernel_launch(void* const* d_in, const int* in_sizes, int n_in,
                              void* d_out, int out_size, void* d_ws, size_t ws_size,
                              hipStream_t stream) {
  (void)in_sizes; (void)n_in; (void)out_size; (void)ws_size;
  const float* x = (const float*)d_in[0];
  float* out = (float*)d_out;
  char* ws = (char*)d_ws;

  char* aq8 = ws;                                                        // 2 MB
  char* pq8 = ws + (size_t)2 * 1024 * 1024;                              // 2 MB
  uint32_t* part = (uint32_t*)(ws + (size_t)4 * 1024 * 1024);            // 5.24 MB
  float* rowloss = (float*)(ws + (size_t)4 * 1024 * 1024 +
                            (size_t)NB * NCG * 5 * sizeof(uint32_t));    // 32 KB

  // JAX: kr = key(1); k1, k2 = split(kr)  (threefry partitionable)
  U2 c0 = tf2x32(0u, 1u, 0u, 0u);
  U2 c1 = tf2x32(0u, 1u, 0u, 1u);
  const uint32_t k1a = c0.x, k1b = c0.y;
  const uint32_t k2a = c1.x, k2b = c1.y;

  prep_kernel<<<NB / 4, 256, 0, stream>>>(x, aq8, pq8);
  dist_topk_kernel<<<2048, 512, 0, stream>>>(aq8, pq8, part);
  merge_loss_kernel<<<NB / 4, 256, 0, stream>>>(x, part, rowloss, k1a, k1b, k2a, k2b);
  finalize_kernel<<<1, 256, 0, stream>>>(rowloss, out);
}